// Round 18
// baseline (402.224 us; speedup 1.0000x reference)
//
#include <hip/hip_runtime.h>
#include <hip/hip_bf16.h>

// ---------------------------------------------------------------------------
// EncoderBlock (differential attention + swiGLU FFN), MI355X / gfx950
// R17: (1) mega-prep: transpose+bias+lambda+LN1 in ONE kernel (4->1 launches).
//      (2) qkv projection moved to gemm128 (768 blocks, 2/CU — gemm256's 192
//      blocks left 64 CUs idle). (3) attn exp2 trick: log2e folded into
//      Wq/bq scale, exp2f replaces expf (drops 16 v_mul/iter; exact identity).
// ---------------------------------------------------------------------------

typedef __attribute__((ext_vector_type(8))) __bf16 bf16x8;
typedef __attribute__((ext_vector_type(4))) float f32x4;

#define GAS __attribute__((address_space(1)))
#define LAS __attribute__((address_space(3)))

__device__ __forceinline__ unsigned short f2bf(float f) {
  unsigned u = __float_as_uint(f);
  u += 0x7fffu + ((u >> 16) & 1u);   // RNE
  return (unsigned short)(u >> 16);
}
__device__ __forceinline__ float bf2f(unsigned short s) {
  return __uint_as_float(((unsigned)s) << 16);
}

// ---------------------------------------------------------------------------
// Mega-prep: blocks [0,7168) transpose the 7 weights; [7168,7180) qkv bias;
// block 7180 lambda; [7181, 7181+4096) LN1 rows.
// ---------------------------------------------------------------------------
__global__ __launch_bounds__(256)
void mega_prep(const float* __restrict__ sWq, const float* __restrict__ sWk,
               const float* __restrict__ sWv, const float* __restrict__ sWo,
               const float* __restrict__ sW1, const float* __restrict__ sWg,
               const float* __restrict__ sW2,
               unsigned short* __restrict__ dstbase,
               const float* __restrict__ bq, const float* __restrict__ bk,
               const float* __restrict__ bv, float* __restrict__ bqkv,
               const float* __restrict__ lq1, const float* __restrict__ lk1,
               const float* __restrict__ lq2, const float* __restrict__ lk2,
               float* __restrict__ lam,
               const float* __restrict__ x, const float* __restrict__ ln1g,
               const float* __restrict__ ln1b, unsigned short* __restrict__ h_bf,
               float qscale) {
  const int id = blockIdx.x;
  if (id >= 7181) {   // LN1 over row (id-7181)
    __shared__ float red[16];
    const int row = id - 7181, tid = threadIdx.x;
    const float4 v = *(const float4*)&x[(size_t)row * 1024 + tid * 4];
    float s = v.x + v.y + v.z + v.w;
    float q = v.x * v.x + v.y * v.y + v.z * v.z + v.w * v.w;
#pragma unroll
    for (int off = 32; off; off >>= 1) {
      s += __shfl_xor(s, off);
      q += __shfl_xor(q, off);
    }
    if ((tid & 63) == 0) { red[tid >> 6] = s; red[8 + (tid >> 6)] = q; }
    __syncthreads();
    s = red[0] + red[1] + red[2] + red[3];
    q = red[8] + red[9] + red[10] + red[11];
    const float mean = s * (1.f / 1024.f);
    const float var = q * (1.f / 1024.f) - mean * mean;
    const float rstd = rsqrtf(var + 1e-5f);
    const float4 gg = *(const float4*)&ln1g[tid * 4];
    const float4 bb = *(const float4*)&ln1b[tid * 4];
    ushort4 o;
    o.x = f2bf((v.x - mean) * rstd * gg.x + bb.x);
    o.y = f2bf((v.y - mean) * rstd * gg.y + bb.y);
    o.z = f2bf((v.z - mean) * rstd * gg.z + bb.z);
    o.w = f2bf((v.w - mean) * rstd * gg.w + bb.w);
    *(ushort4*)&h_bf[(size_t)row * 1024 + tid * 4] = o;
    return;
  }
  if (id == 7180) {   // lambda
    if (threadIdx.x < 512) {
      const int w = threadIdx.x >> 6, d = threadIdx.x & 63;
      // only 256 threads; do 8 heads with 32 lanes each? Keep simple:
    }
    // 256 threads: head h = tid>>5 (8 heads x 32 lanes), reduce 64 dims by 2/lane
    const int hh = threadIdx.x >> 5, d = (threadIdx.x & 31) * 2;
    float a = lq1[hh * 64 + d] * lk1[hh * 64 + d] + lq1[hh * 64 + d + 1] * lk1[hh * 64 + d + 1];
    float c = lq2[hh * 64 + d] * lk2[hh * 64 + d] + lq2[hh * 64 + d + 1] * lk2[hh * 64 + d + 1];
#pragma unroll
    for (int off = 16; off; off >>= 1) {
      a += __shfl_xor(a, off);
      c += __shfl_xor(c, off);
    }
    if ((threadIdx.x & 31) == 0) lam[hh] = __expf(a) - __expf(c) + 0.8f;
    return;
  }
  if (id >= 7168) {   // qkv bias
    const int i = (id - 7168) * 256 + threadIdx.x;
    if (i < 1024) bqkv[i] = bq[i] * qscale;
    else if (i < 2048) bqkv[i] = bk[i - 1024];
    else bqkv[i] = bv[i - 2048];
    return;
  }
  const float* W;
  int K, N, t;
  size_t doff;
  float scale = 1.0f;
  if (id < 256)       { W = sWq; K = 1024; N = 1024; t = id;        doff = 0;        scale = qscale; }
  else if (id < 512)  { W = sWk; K = 1024; N = 1024; t = id - 256;  doff = 1048576;  }
  else if (id < 768)  { W = sWv; K = 1024; N = 1024; t = id - 512;  doff = 2097152;  }
  else if (id < 1024) { W = sWo; K = 1024; N = 1024; t = id - 768;  doff = 3145728;  }
  else if (id < 2048) { W = sW1; K = 1024; N = 4096; t = id - 1024; doff = 4194304;  }
  else if (id < 6144) { W = sWg; K = 4096; N = 4096; t = id - 2048; doff = 8388608;  }
  else                { W = sW2; K = 4096; N = 1024; t = id - 6144; doff = 25165824; }
  unsigned short* WT = dstbase + doff;
  const int nx = N >> 6;
  const int n0 = (t % nx) * 64, k0 = (t / nx) * 64;

  __shared__ float tile[64][65];
  const int tr = threadIdx.x >> 4, tc = (threadIdx.x & 15) * 4;
#pragma unroll
  for (int i = 0; i < 4; ++i) {
    const float4 v = *(const float4*)&W[(size_t)(k0 + tr + i * 16) * N + n0 + tc];
    tile[tr + i * 16][tc + 0] = v.x;
    tile[tr + i * 16][tc + 1] = v.y;
    tile[tr + i * 16][tc + 2] = v.z;
    tile[tr + i * 16][tc + 3] = v.w;
  }
  __syncthreads();
#pragma unroll
  for (int i = 0; i < 4; ++i) {
    const int n = tr + i * 16;
    ushort4 o;
    o.x = f2bf(tile[tc + 0][n] * scale);
    o.y = f2bf(tile[tc + 1][n] * scale);
    o.z = f2bf(tile[tc + 2][n] * scale);
    o.w = f2bf(tile[tc + 3][n] * scale);
    *(ushort4*)&WT[(size_t)(n0 + n) * K + k0 + tc] = o;
  }
}

// ---------------------------------------------------------------------------
// kv_prep: K copy -> KP, V transpose -> VT (per (bh, 64-row s-chunk)).
// ---------------------------------------------------------------------------
__global__ __launch_bounds__(256)
void kv_prep(const unsigned short* __restrict__ qkv, unsigned short* __restrict__ KP,
             unsigned short* __restrict__ VT) {
  __shared__ unsigned short tile[128][66];
  const int bh = blockIdx.y, b = bh >> 3, h = bh & 7;
  const int s0 = blockIdx.x * 64;
  const size_t inbase = (size_t)b * 2048 * 3072 + h * 128;
  const int tr = threadIdx.x >> 4, tc = (threadIdx.x & 15) * 8;
#pragma unroll
  for (int i = 0; i < 4; ++i) {
    const int s = s0 + tr + i * 16;
    *(uint4*)&KP[((size_t)bh * 2048 + s) * 128 + tc] =
        *(const uint4*)&qkv[inbase + (size_t)s * 3072 + 1024 + tc];
  }
#pragma unroll
  for (int i = 0; i < 4; ++i) {
    const int r = tr + i * 16;
    const uint4 v = *(const uint4*)&qkv[inbase + (size_t)(s0 + r) * 3072 + 2048 + tc];
    const unsigned short* pv = (const unsigned short*)&v;
#pragma unroll
    for (int jj = 0; jj < 8; ++jj) tile[tc + jj][r] = pv[jj];
  }
  __syncthreads();
  const int e = threadIdx.x >> 1, sh = (threadIdx.x & 1) * 32;
#pragma unroll
  for (int i = 0; i < 4; ++i) {
    ushort4 o0, o1;
    o0.x = tile[e][sh + i * 8 + 0]; o0.y = tile[e][sh + i * 8 + 1];
    o0.z = tile[e][sh + i * 8 + 2]; o0.w = tile[e][sh + i * 8 + 3];
    o1.x = tile[e][sh + i * 8 + 4]; o1.y = tile[e][sh + i * 8 + 5];
    o1.z = tile[e][sh + i * 8 + 6]; o1.w = tile[e][sh + i * 8 + 7];
    *(ushort4*)&VT[((size_t)bh * 128 + e) * 2048 + s0 + sh + i * 8] = o0;
    *(ushort4*)&VT[((size_t)bh * 128 + e) * 2048 + s0 + sh + i * 8 + 4] = o1;
  }
}

// ---------------------------------------------------------------------------
// LayerNorm over rows of 1024 (bf16 out) — used for LN2.
// ---------------------------------------------------------------------------
__global__ __launch_bounds__(256)
void ln_kernel(const float* __restrict__ x, const float* __restrict__ g,
               const float* __restrict__ bsh, unsigned short* __restrict__ obf) {
  __shared__ float red[16];
  const int row = blockIdx.x, tid = threadIdx.x;
  const float4 v = *(const float4*)&x[(size_t)row * 1024 + tid * 4];
  float s = v.x + v.y + v.z + v.w;
  float q = v.x * v.x + v.y * v.y + v.z * v.z + v.w * v.w;
#pragma unroll
  for (int off = 32; off; off >>= 1) {
    s += __shfl_xor(s, off);
    q += __shfl_xor(q, off);
  }
  if ((tid & 63) == 0) {
    red[tid >> 6] = s;
    red[8 + (tid >> 6)] = q;
  }
  __syncthreads();
  s = red[0] + red[1] + red[2] + red[3];
  q = red[8] + red[9] + red[10] + red[11];
  const float mean = s * (1.f / 1024.f);
  const float var = q * (1.f / 1024.f) - mean * mean;
  const float rstd = rsqrtf(var + 1e-5f);
  const float4 gg = *(const float4*)&g[tid * 4];
  const float4 bb = *(const float4*)&bsh[tid * 4];
  ushort4 o;
  o.x = f2bf((v.x - mean) * rstd * gg.x + bb.x);
  o.y = f2bf((v.y - mean) * rstd * gg.y + bb.y);
  o.z = f2bf((v.z - mean) * rstd * gg.z + bb.z);
  o.w = f2bf((v.w - mean) * rstd * gg.w + bb.w);
  *(ushort4*)&obf[(size_t)row * 1024 + tid * 4] = o;
}

// ---------------------------------------------------------------------------
// GEMM 128x128, 4-wave, BK=64, deep pipeline (R15 staging schedule).
// EPI 0: bf16 out = acc + bias. EPI 1: fp32 = resf + acc + bias.
// EPI 2: fp32 = bf2f(resb) + acc + bias.
// ---------------------------------------------------------------------------
template <int EPI>
__global__ __launch_bounds__(256)
void gemm128(const unsigned short* __restrict__ A,
             const unsigned short* __restrict__ BT,
             const float* __restrict__ bias,
             const float* __restrict__ resf,
             const unsigned short* __restrict__ resb,
             void* __restrict__ Cout, int M, int N, int K, float bscale) {
  __shared__ unsigned short lds[32768];
  const int tid = threadIdx.x;
  const int w = tid >> 6, ln = tid & 63, lg = ln >> 4, lc = ln & 15;
  const int wm = w >> 1, wn = w & 1;
  const int nwg = gridDim.x * gridDim.y;
  const int linear = blockIdx.y * gridDim.x + blockIdx.x;
  const int swzb = (linear & 7) * (nwg >> 3) + (linear >> 3);
  const int m0 = (swzb / gridDim.x) * 128, n0 = (swzb % gridDim.x) * 128;

  f32x4 acc[4][4];
#pragma unroll
  for (int i = 0; i < 4; ++i)
#pragma unroll
    for (int j = 0; j < 4; ++j) acc[i][j] = (f32x4)0.f;

  auto stage_half = [&](int tensor, int j, int hh) {
    const unsigned short* base = tensor ? BT : A;
    const int row0 = (tensor ? n0 : m0) + hh * 64;
    const int slot = tensor * 4 + (j & 1) * 2 + hh;
#pragma unroll
    for (int c = 0; c < 2; ++c) {
      const int chunk = w * 2 + c;
      const int L = chunk * 1024 + ln * 16;
      const int r = L >> 7, inner = L & 127;
      const char* src = (const char*)(base + (size_t)(row0 + r) * K + j * 64) +
                        (inner ^ ((r & 7) << 4));
      __builtin_amdgcn_global_load_lds((GAS void*)src,
          (LAS void*)((char*)lds + slot * 8192 + chunk * 1024), 16, 0, 0);
    }
  };
  auto read_a = [&](int j, int mf, int ks) -> bf16x8 {
    const int r = mf * 16 + lc;
    const int slot = (j & 1) * 2 + wm;
    const int cb = ks * 64 + lg * 16;
    return *(const bf16x8*)((const char*)lds + slot * 8192 + r * 128 +
                            (cb ^ ((r & 7) << 4)));
  };
  auto read_b = [&](int j, int nf, int ks) -> bf16x8 {
    const int R = wn * 64 + nf * 16 + lc;
    const int slot = 4 + (j & 1) * 2 + (R >> 6);
    const int r = R & 63;
    const int cb = ks * 64 + lg * 16;
    return *(const bf16x8*)((const char*)lds + slot * 8192 + r * 128 +
                            (cb ^ ((r & 7) << 4)));
  };

  const int nkt = K / 64;

  stage_half(0, 0, 0); stage_half(0, 0, 1);
  stage_half(1, 0, 0); stage_half(1, 0, 1);
  stage_half(1, 1, 0); stage_half(1, 1, 1);
  asm volatile("s_waitcnt vmcnt(0)" ::: "memory");
  __builtin_amdgcn_s_barrier();

  bf16x8 bfr[4][2];
  for (int it = 0; it < nkt / 2; ++it) {
    const int J = it * 2;
#pragma unroll
    for (int half = 0; half < 2; ++half) {
      const int jc = J + half;
#pragma unroll
      for (int q = 0; q < 2; ++q) {
        if (q == 0) {
#pragma unroll
          for (int nf = 0; nf < 4; ++nf)
#pragma unroll
            for (int ks = 0; ks < 2; ++ks) bfr[nf][ks] = read_b(jc, nf, ks);
        }
        bf16x8 afr[2][2];
#pragma unroll
        for (int mm = 0; mm < 2; ++mm)
#pragma unroll
          for (int ks = 0; ks < 2; ++ks) afr[mm][ks] = read_a(jc, q * 2 + mm, ks);
        if (half == 0) {
          if (q == 0) { stage_half(0, J + 1, 0); stage_half(0, J + 1, 1); }
          else if (J + 2 < nkt) { stage_half(1, J + 2, 0); stage_half(1, J + 2, 1); }
        } else {
          if (q == 0) { if (J + 2 < nkt) { stage_half(0, J + 2, 0); stage_half(0, J + 2, 1); } }
          else if (J + 3 < nkt) { stage_half(1, J + 3, 0); stage_half(1, J + 3, 1); }
        }
        __builtin_amdgcn_s_barrier();
        asm volatile("s_waitcnt lgkmcnt(0)" ::: "memory");
        __builtin_amdgcn_sched_barrier(0);
        __builtin_amdgcn_s_setprio(1);
#pragma unroll
        for (int mm = 0; mm < 2; ++mm)
#pragma unroll
          for (int nf = 0; nf < 4; ++nf)
#pragma unroll
            for (int ks = 0; ks < 2; ++ks)
              acc[q * 2 + mm][nf] = __builtin_amdgcn_mfma_f32_16x16x32_bf16(
                  afr[mm][ks], bfr[nf][ks], acc[q * 2 + mm][nf], 0, 0, 0);
        __builtin_amdgcn_s_setprio(0);
        if (q == 1) {
          if ((half == 0 && J + 2 < nkt) || (half == 1 && J + 3 < nkt))
            asm volatile("s_waitcnt vmcnt(4)" ::: "memory");
          else
            asm volatile("s_waitcnt vmcnt(0)" ::: "memory");
        }
        __builtin_amdgcn_s_barrier();
      }
    }
  }

#pragma unroll
  for (int mf = 0; mf < 4; ++mf) {
#pragma unroll
    for (int nf = 0; nf < 4; ++nf) {
      const int c = n0 + wn * 64 + nf * 16 + lc;
      const float bc = bias[c] * bscale;
#pragma unroll
      for (int jj = 0; jj < 4; ++jj) {
        const int r = m0 + wm * 64 + mf * 16 + lg * 4 + jj;
        const size_t idx = (size_t)r * N + c;
        const float v = acc[mf][nf][jj] + bc;
        if (EPI == 1) {
          ((float*)Cout)[idx] = resf[idx] + v;
        } else if (EPI == 2) {
          ((float*)Cout)[idx] = bf2f(resb[idx]) + v;
        } else {
          ((unsigned short*)Cout)[idx] = f2bf(v);
        }
      }
    }
  }
}

// ---------------------------------------------------------------------------
// GEMM 256x256, 8-wave, BK=64, 8-phase deep pipeline (m201 template).
// ---------------------------------------------------------------------------
template <int EPI>
__global__ __launch_bounds__(512)
void gemm256(const unsigned short* __restrict__ A,
             const unsigned short* __restrict__ BT,
             const float* __restrict__ bias,
             const unsigned short* __restrict__ gate_u,
             unsigned short* __restrict__ Cout, int M, int N, int K) {
  __shared__ unsigned short lds[65536];
  const int tid = threadIdx.x;
  const int w = tid >> 6, ln = tid & 63, lg = ln >> 4, lc = ln & 15;
  const int wm = w >> 2, wn = w & 3;
  const int nwg = gridDim.x * gridDim.y;
  const int linear = blockIdx.y * gridDim.x + blockIdx.x;
  const int swzb = (linear & 7) * (nwg >> 3) + (linear >> 3);
  const int m0 = (swzb / gridDim.x) * 256, n0 = (swzb % gridDim.x) * 256;

  f32x4 acc[8][4];
#pragma unroll
  for (int i = 0; i < 8; ++i)
#pragma unroll
    for (int j = 0; j < 4; ++j) acc[i][j] = (f32x4)0.f;

  auto stage_half = [&](int tensor, int j, int hh) {
    const unsigned short* base = tensor ? BT : A;
    const int row0 = (tensor ? n0 : m0) + hh * 128;
    const int slot = tensor * 4 + (j & 1) * 2 + hh;
#pragma unroll
    for (int c = 0; c < 2; ++c) {
      const int chunk = w * 2 + c;
      const int L = chunk * 1024 + ln * 16;
      const int r = L >> 7, inner = L & 127;
      const char* src = (const char*)(base + (size_t)(row0 + r) * K + j * 64) +
                        (inner ^ ((r & 7) << 4));
      __builtin_amdgcn_global_load_lds((GAS void*)src,
          (LAS void*)((char*)lds + slot * 16384 + chunk * 1024), 16, 0, 0);
    }
  };
  auto read_a = [&](int j, int mf, int ks) -> bf16x8 {
    const int r = mf * 16 + lc;
    const int slot = (j & 1) * 2 + wm;
    const int cb = ks * 64 + lg * 16;
    return *(const bf16x8*)((const char*)lds + slot * 16384 + r * 128 +
                            (cb ^ ((r & 7) << 4)));
  };
  auto read_b = [&](int j, int nf, int ks) -> bf16x8 {
    const int R = wn * 64 + nf * 16 + lc;
    const int slot = 4 + (j & 1) * 2 + (R >> 7);
    const int r = R & 127;
    const int cb = ks * 64 + lg * 16;
    return *(const bf16x8*)((const char*)lds + slot * 16384 + r * 128 +
                            (cb ^ ((r & 7) << 4)));
  };

  const int nkt = K / 64;

  stage_half(0, 0, 0); stage_half(0, 0, 1);
  stage_half(1, 0, 0); stage_half(1, 0, 1);
  stage_half(1, 1, 0); stage_half(1, 1, 1);
  asm volatile("s_waitcnt vmcnt(0)" ::: "memory");
  __builtin_amdgcn_s_barrier();

  bf16x8 bfr[4][2];
  for (int it = 0; it < nkt / 2; ++it) {
    const int J = it * 2;
#pragma unroll
    for (int half = 0; half < 2; ++half) {
      const int jc = J + half;
#pragma unroll
      for (int q = 0; q < 4; ++q) {
        if (q == 0) {
#pragma unroll
          for (int nf = 0; nf < 4; ++nf)
#pragma unroll
            for (int ks = 0; ks < 2; ++ks) bfr[nf][ks] = read_b(jc, nf, ks);
        }
        bf16x8 afr[2][2];
#pragma unroll
        for (int mm = 0; mm < 2; ++mm)
#pragma unroll
          for (int ks = 0; ks < 2; ++ks) afr[mm][ks] = read_a(jc, q * 2 + mm, ks);
        if (half == 0) {
          if (q == 0) stage_half(0, J + 1, 0);
          if (q == 1) stage_half(0, J + 1, 1);
          if (q == 2 && J + 2 < nkt) stage_half(1, J + 2, 0);
          if (q == 3 && J + 2 < nkt) stage_half(1, J + 2, 1);
        } else {
          if (q == 0 && J + 2 < nkt) stage_half(0, J + 2, 0);
          if (q == 1 && J + 2 < nkt) stage_half(0, J + 2, 1);
          if (q == 2 && J + 3 < nkt) stage_half(1, J + 3, 0);
          if (q == 3 && J + 3 < nkt) stage_half(1, J + 3, 1);
        }
        __builtin_amdgcn_s_barrier();
        asm volatile("s_waitcnt lgkmcnt(0)" ::: "memory");
        __builtin_amdgcn_sched_barrier(0);
        __builtin_amdgcn_s_setprio(1);
#pragma unroll
        for (int mm = 0; mm < 2; ++mm)
#pragma unroll
          for (int nf = 0; nf < 4; ++nf)
#pragma unroll
            for (int ks = 0; ks < 2; ++ks)
              acc[q * 2 + mm][nf] = __builtin_amdgcn_mfma_f32_16x16x32_bf16(
                  afr[mm][ks], bfr[nf][ks], acc[q * 2 + mm][nf], 0, 0, 0);
        __builtin_amdgcn_s_setprio(0);
        if (q == 3) asm volatile("s_waitcnt vmcnt(4)" ::: "memory");
        __builtin_amdgcn_s_barrier();
      }
    }
  }

#pragma unroll
  for (int mf = 0; mf < 8; ++mf) {
#pragma unroll
    for (int nf = 0; nf < 4; ++nf) {
      const int c = n0 + wn * 64 + nf * 16 + lc;
      const float bc = bias[c];
#pragma unroll
      for (int jj = 0; jj < 4; ++jj) {
        const int r = m0 + wm * 128 + mf * 16 + lg * 4 + jj;
        const size_t idx = (size_t)r * N + c;
        const float v = acc[mf][nf][jj] + bc;
        if (EPI == 0) {
          Cout[idx] = f2bf(v);
        } else {
          const float uu = bf2f(gate_u[idx]);
          const float sw = v / (1.f + __expf(-v));   // silu
          Cout[idx] = f2bf(uu * sw);
        }
      }
    }
  }
}

// ---------------------------------------------------------------------------
// Differential attention, NT=1, fused lambda-diff + GroupNorm epilogue.
// exp2 trick: scores pre-scaled by log2e (in Wq/bq); P = exp2(S).
// ---------------------------------------------------------------------------
__global__ __launch_bounds__(256)
void attn_kernel(const unsigned short* __restrict__ q,
                 const unsigned short* __restrict__ KP,
                 const unsigned short* __restrict__ VT,
                 const float* __restrict__ lam,
                 const float* __restrict__ gn_w, const float* __restrict__ gn_b,
                 unsigned short* __restrict__ o) {
  constexpr int S = 2048;
  constexpr int QS = 3072;
  __shared__ unsigned short k_tile[2][32 * 128];
  __shared__ unsigned short v_tile[2][128 * 32];
  __shared__ unsigned short p_lds[4][2][512];
  const int tid = threadIdx.x, w = tid >> 6, ln = tid & 63, lg = ln >> 4, lc = ln & 15;
  const int id = blockIdx.x;
  const int bh = (id & 7) + 8 * ((id >> 8) & 1);
  const int qt = (id >> 3) & 31;
  const int h = bh & 7, b = bh >> 3;
  const size_t chan = (size_t)b * S * QS + h * 128;
  const size_t ochan = (size_t)b * S * 1024 + h * 128;
  const size_t kpbase = (size_t)bh * S * 128;
  const size_t vtbase = (size_t)bh * 128 * S;
  const int qrow = qt * 64 + w * 16 + lc;

  bf16x8 qf[2][2];
#pragma unroll
  for (int p = 0; p < 2; ++p)
#pragma unroll
    for (int ks = 0; ks < 2; ++ks)
      qf[p][ks] = *(const bf16x8*)&q[chan + (size_t)qrow * QS + p * 64 + ks * 32 + lg * 8];

  f32x4 O[2][8];
#pragma unroll
  for (int p = 0; p < 2; ++p)
#pragma unroll
    for (int ef = 0; ef < 8; ++ef) O[p][ef] = (f32x4)0.f;
  float lsum[2][4];
#pragma unroll
  for (int p = 0; p < 2; ++p)
#pragma unroll
    for (int j = 0; j < 4; ++j) lsum[p][j] = 0.f;

  const int prd = ((lc * 64 + lg * 16) ^ ((lc & 7) << 4)) >> 1;

  auto stage = [&](int buf, int t0) {
#pragma unroll
    for (int c = 0; c < 2; ++c) {
      {
        const int L = (w * 2 + c) * 1024 + ln * 16;
        const int r = L >> 8, inner = L & 255;
        const char* src = (const char*)(KP + kpbase + (size_t)(t0 + r) * 128) +
                          (inner ^ ((r & 7) << 4));
        __builtin_amdgcn_global_load_lds((GAS void*)src,
            (LAS void*)((char*)&k_tile[buf][0] + (w * 2 + c) * 1024), 16, 0, 0);
      }
      {
        const int L = (w * 2 + c) * 1024 + ln * 16;
        const int e = L >> 6, inner = L & 63;
        const char* src = (const char*)(VT + vtbase + (size_t)e * S + t0) +
                          (inner ^ ((e & 3) << 4));
        __builtin_amdgcn_global_load_lds((GAS void*)src,
            (LAS void*)((char*)&v_tile[buf][0] + (w * 2 + c) * 1024), 16, 0, 0);
      }
    }
  };

  auto compute = [&](int buf) {
    const char* kb = (const char*)&k_tile[buf][0];
    const char* vb = (const char*)&v_tile[buf][0];
#pragma unroll
    for (int p = 0; p < 2; ++p) {
      bf16x8 kf[2][2];
#pragma unroll
      for (int tf = 0; tf < 2; ++tf) {
        const int r = tf * 16 + lc;
#pragma unroll
        for (int ks = 0; ks < 2; ++ks)
          kf[tf][ks] = *(const bf16x8*)(kb + r * 256 +
                          ((p * 128 + ks * 64 + lg * 16) ^ ((r & 7) << 4)));
      }
      f32x4 sfr[2];
      __builtin_amdgcn_s_setprio(1);
#pragma unroll
      for (int tf = 0; tf < 2; ++tf) {
        f32x4 acc = (f32x4)0.f;
#pragma unroll
        for (int ks = 0; ks < 2; ++ks)
          acc = __builtin_amdgcn_mfma_f32_16x16x32_bf16(qf[p][ks], kf[tf][ks], acc, 0, 0, 0);
        sfr[tf] = acc;
      }
      __builtin_amdgcn_s_setprio(0);
#pragma unroll
      for (int tf = 0; tf < 2; ++tf)
#pragma unroll
        for (int j = 0; j < 4; ++j) {
          const float e = exp2f(sfr[tf][j]);   // P = 2^S (log2e folded into q)
          lsum[p][j] += e;
          const int qq = lg * 4 + j;
          const int wi = ((qq * 64 + (tf * 16 + lc) * 2) ^ ((qq & 7) << 4)) >> 1;
          p_lds[w][p][wi] = f2bf(e);
        }
    }
    bf16x8 pa[2];
#pragma unroll
    for (int p = 0; p < 2; ++p)
      pa[p] = *(const bf16x8*)&p_lds[w][p][prd];
#pragma unroll
    for (int half = 0; half < 2; ++half) {
      bf16x8 vf[4];
#pragma unroll
      for (int ef = 0; ef < 4; ++ef) {
        const int e = (half * 4 + ef) * 16 + lc;
        vf[ef] = *(const bf16x8*)(vb + e * 64 + ((lg * 16) ^ ((e & 3) << 4)));
      }
      __builtin_amdgcn_s_setprio(1);
#pragma unroll
      for (int p = 0; p < 2; ++p)
#pragma unroll
        for (int ef = 0; ef < 4; ++ef)
          O[p][half * 4 + ef] = __builtin_amdgcn_mfma_f32_16x16x32_bf16(
              pa[p], vf[ef], O[p][half * 4 + ef], 0, 0, 0);
      __builtin_amdgcn_s_setprio(0);
    }
  };

  stage(0, 0);
  int cur = 0;
  for (int it = 0; it < 64; ++it) {
    if (it < 63) {
      stage(cur ^ 1, (it + 1) * 32);
      asm volatile("s_waitcnt vmcnt(4)" ::: "memory");
    } else {
      asm volatile("s_waitcnt vmcnt(0)" ::: "memory");
    }
    __builtin_amdgcn_s_barrier();
    compute(cur);
    __builtin_amdgcn_s_barrier();
    cur ^= 1;
  }

  // fused epilogue
#pragma unroll
  for (int p = 0; p < 2; ++p)
#pragma unroll
    for (int j = 0; j < 4; ++j) {
      float s = lsum[p][j];
      s += __shfl_xor(s, 1);
      s += __shfl_xor(s, 2);
      s += __shfl_xor(s, 4);
      s += __shfl_xor(s, 8);
      lsum[p][j] = s;
    }
  const float lamh = lam[h];
#pragma unroll
  for (int j = 0; j < 4; ++j) {
    const float inv1 = 1.f / lsum[0][j];
    const float inv2 = lamh / lsum[1][j];
    float dv[8], sum = 0.f, sq = 0.f;
#pragma unroll
    for (int ef = 0; ef < 8; ++ef) {
      dv[ef] = O[0][ef][j] * inv1 - O[1][ef][j] * inv2;
      sum += dv[ef];
      sq += dv[ef] * dv[ef];
    }
    sum += __shfl_xor(sum, 1); sq += __shfl_xor(sq, 1);
    sum += __shfl_xor(sum, 2); sq += __shfl_xor(sq, 2);
    sum += __shfl_xor(sum, 4); sq += __shfl_xor(sq, 4);
    sum += __shfl_xor(sum, 8); sq += __shfl_xor(sq, 8);
    const float mean = sum * (1.f / 128.f);
    const float var = sq * (1.f / 128.f) - mean * mean;
    const float rstd = rsqrtf(var + 1e-5f);
    const int row = qt * 64 + w * 16 + lg * 4 + j;
#pragma unroll
    for (int ef = 0; ef < 8; ++ef) {
      const int e = ef * 16 + lc;
      const float val = (dv[ef] - mean) * rstd * gn_w[h * 128 + e] + gn_b[h * 128 + e];
      o[ochan + (size_t)row * 1024 + e] = f2bf(val * 0.2f);
    }
  }
}

// ---------------------------------------------------------------------------
extern "C" void kernel_launch(void* const* d_in, const int* in_sizes, int n_in,
                              void* d_out, int out_size, void* d_ws, size_t ws_size,
                              hipStream_t stream) {
  (void)in_sizes; (void)n_in; (void)out_size; (void)ws_size;
  const float* x    = (const float*)d_in[0];
  const float* ln1g = (const float*)d_in[1];
  const float* ln1b = (const float*)d_in[2];
  const float* ln2g = (const float*)d_in[3];
  const float* ln2b = (const float*)d_in[4];
  const float* Wq   = (const float*)d_in[5];
  const float* bq   = (const float*)d_in[6];
  const float* Wk   = (const float*)d_in[7];
  const float* bk   = (const float*)d_in[8];
  const float* Wv   = (const float*)d_in[9];
  const float* bv   = (const float*)d_in[10];
  const float* Wo   = (const float*)d_in[11];
  const float* bo   = (const float*)d_in[12];
  const float* lq1  = (const float*)d_in[13];
  const float* lk1  = (const float*)d_in[14];
  const float* lq2  = (const float*)d_in[15];
  const float* lk2  = (const float*)d_in[16];
  const float* gnw  = (const float*)d_in[17];
  const float* gnb  = (const float*)d_in[18];
  const float* W1   = (const float*)d_in[19];
  const float* b1   = (const float*)d_in[20];
  const float* Wg   = (const float*)d_in[21];
  const float* bg   = (const float*)d_in[22];
  const float* W2   = (const float*)d_in[23];
  const float* b2   = (const float*)d_in[24];

  const int B = 2, S = 2048, D = 1024, F = 4096;
  const int M = B * S;  // 4096
  const float qscale = 0.125f * 1.4426950408889634f;   // 1/sqrt(64) * log2e

  char* ws = (char*)d_ws;
  size_t off = 0;
  auto alloc = [&](size_t bytes) {
    char* p = ws + off;
    off += (bytes + 255) & ~(size_t)255;
    return p;
  };
  unsigned short* WqkvT = (unsigned short*)alloc((size_t)3 * D * D * 2);
  unsigned short* WoT = (unsigned short*)alloc((size_t)D * D * 2);
  unsigned short* W1T = (unsigned short*)alloc((size_t)F * D * 2);
  unsigned short* WgT = (unsigned short*)alloc((size_t)F * F * 2);
  unsigned short* W2T = (unsigned short*)alloc((size_t)D * F * 2);
  float*          lamw= (float*)alloc(256);
  float*          bqkv= (float*)alloc(3072 * 4);
  unsigned short* h_bf= (unsigned short*)alloc((size_t)M * D * 2);
  unsigned short* qkv = (unsigned short*)alloc((size_t)M * 3 * D * 2);
  unsigned short* o_bf= (unsigned short*)alloc((size_t)M * D * 2);
  float*          x1  = (float*)alloc((size_t)M * D * 4);
  unsigned short* x2b = (unsigned short*)alloc((size_t)M * D * 2);
  unsigned short* u_bf= (unsigned short*)alloc((size_t)M * F * 2);
  unsigned short* w_bf= h_bf;   // gated act reuses h span

  unsigned short* KP = (unsigned short*)x1;
  unsigned short* VT = u_bf + (size_t)12 * 1024 * 1024;

  // --- fused prep: weights + bias + lambda + LN1 ---
  mega_prep<<<7181 + M, 256, 0, stream>>>(Wq, Wk, Wv, Wo, W1, Wg, W2, WqkvT,
                                          bq, bk, bv, bqkv,
                                          lq1, lk1, lq2, lk2, lamw,
                                          x, ln1g, ln1b, h_bf, qscale);

  // --- attention sublayer ---
  gemm128<0><<<dim3(3 * D / 128, M / 128), 256, 0, stream>>>(h_bf, WqkvT, bqkv, nullptr, nullptr, qkv, M, 3 * D, D, 1.0f);
  kv_prep<<<dim3(S / 64, 16), 256, 0, stream>>>(qkv, KP, VT);
  attn_kernel<<<dim3(512), 256, 0, stream>>>(qkv, KP, VT, lamw, gnw, gnb, o_bf);
  gemm128<1><<<dim3(D / 128, M / 128), 256, 0, stream>>>(o_bf, WoT, bo, x, nullptr, x1, M, D, D, 1.0f);

  // --- FFN sublayer ---
  ln_kernel<<<M, 256, 0, stream>>>(x1, ln2g, ln2b, x2b);
  gemm256<0><<<dim3(F / 256, M / 256), 512, 0, stream>>>(x2b, W1T, b1, nullptr, u_bf, M, F, D);
  gemm256<2><<<dim3(F / 256, M / 256), 512, 0, stream>>>(u_bf, WgT, bg, u_bf, w_bf, M, F, F);
  gemm128<2><<<dim3(D / 128, M / 128), 256, 0, stream>>>(w_bf, W2T, b2, nullptr, x2b, (float*)d_out, M, D, F, 1.0f);
}

// Round 19
// 394.112 us; speedup vs baseline: 1.0206x; 1.0206x over previous
//
#include <hip/hip_runtime.h>
#include <hip/hip_bf16.h>

// ---------------------------------------------------------------------------
// EncoderBlock (differential attention + swiGLU FFN), MI355X / gfx950
// R18: revert R17's qkv->gemm128 move (regression: gemm128's barrier/MFMA
//      ratio at K=1024 outweighed the grid-occupancy gain). qkv back on
//      gemm256. mega_prep + exp2 retained.
// ---------------------------------------------------------------------------

typedef __attribute__((ext_vector_type(8))) __bf16 bf16x8;
typedef __attribute__((ext_vector_type(4))) float f32x4;

#define GAS __attribute__((address_space(1)))
#define LAS __attribute__((address_space(3)))

__device__ __forceinline__ unsigned short f2bf(float f) {
  unsigned u = __float_as_uint(f);
  u += 0x7fffu + ((u >> 16) & 1u);   // RNE
  return (unsigned short)(u >> 16);
}
__device__ __forceinline__ float bf2f(unsigned short s) {
  return __uint_as_float(((unsigned)s) << 16);
}

// ---------------------------------------------------------------------------
// Mega-prep: [0,7168) weight transposes; [7168,7180) qkv bias; 7180 lambda;
// [7181, 7181+4096) LN1 rows.
// ---------------------------------------------------------------------------
__global__ __launch_bounds__(256)
void mega_prep(const float* __restrict__ sWq, const float* __restrict__ sWk,
               const float* __restrict__ sWv, const float* __restrict__ sWo,
               const float* __restrict__ sW1, const float* __restrict__ sWg,
               const float* __restrict__ sW2,
               unsigned short* __restrict__ dstbase,
               const float* __restrict__ bq, const float* __restrict__ bk,
               const float* __restrict__ bv, float* __restrict__ bqkv,
               const float* __restrict__ lq1, const float* __restrict__ lk1,
               const float* __restrict__ lq2, const float* __restrict__ lk2,
               float* __restrict__ lam,
               const float* __restrict__ x, const float* __restrict__ ln1g,
               const float* __restrict__ ln1b, unsigned short* __restrict__ h_bf,
               float qscale) {
  const int id = blockIdx.x;
  if (id >= 7181) {   // LN1 over row (id-7181)
    __shared__ float red[16];
    const int row = id - 7181, tid = threadIdx.x;
    const float4 v = *(const float4*)&x[(size_t)row * 1024 + tid * 4];
    float s = v.x + v.y + v.z + v.w;
    float q = v.x * v.x + v.y * v.y + v.z * v.z + v.w * v.w;
#pragma unroll
    for (int off = 32; off; off >>= 1) {
      s += __shfl_xor(s, off);
      q += __shfl_xor(q, off);
    }
    if ((tid & 63) == 0) { red[tid >> 6] = s; red[8 + (tid >> 6)] = q; }
    __syncthreads();
    s = red[0] + red[1] + red[2] + red[3];
    q = red[8] + red[9] + red[10] + red[11];
    const float mean = s * (1.f / 1024.f);
    const float var = q * (1.f / 1024.f) - mean * mean;
    const float rstd = rsqrtf(var + 1e-5f);
    const float4 gg = *(const float4*)&ln1g[tid * 4];
    const float4 bb = *(const float4*)&ln1b[tid * 4];
    ushort4 o;
    o.x = f2bf((v.x - mean) * rstd * gg.x + bb.x);
    o.y = f2bf((v.y - mean) * rstd * gg.y + bb.y);
    o.z = f2bf((v.z - mean) * rstd * gg.z + bb.z);
    o.w = f2bf((v.w - mean) * rstd * gg.w + bb.w);
    *(ushort4*)&h_bf[(size_t)row * 1024 + tid * 4] = o;
    return;
  }
  if (id == 7180) {   // lambda: 8 heads x 32 lanes, 2 dims/lane
    const int hh = threadIdx.x >> 5, d = (threadIdx.x & 31) * 2;
    float a = lq1[hh * 64 + d] * lk1[hh * 64 + d] + lq1[hh * 64 + d + 1] * lk1[hh * 64 + d + 1];
    float c = lq2[hh * 64 + d] * lk2[hh * 64 + d] + lq2[hh * 64 + d + 1] * lk2[hh * 64 + d + 1];
#pragma unroll
    for (int off = 16; off; off >>= 1) {
      a += __shfl_xor(a, off);
      c += __shfl_xor(c, off);
    }
    if ((threadIdx.x & 31) == 0) lam[hh] = __expf(a) - __expf(c) + 0.8f;
    return;
  }
  if (id >= 7168) {   // qkv bias
    const int i = (id - 7168) * 256 + threadIdx.x;
    if (i < 1024) bqkv[i] = bq[i] * qscale;
    else if (i < 2048) bqkv[i] = bk[i - 1024];
    else bqkv[i] = bv[i - 2048];
    return;
  }
  const float* W;
  int K, N, t;
  size_t doff;
  float scale = 1.0f;
  if (id < 256)       { W = sWq; K = 1024; N = 1024; t = id;        doff = 0;        scale = qscale; }
  else if (id < 512)  { W = sWk; K = 1024; N = 1024; t = id - 256;  doff = 1048576;  }
  else if (id < 768)  { W = sWv; K = 1024; N = 1024; t = id - 512;  doff = 2097152;  }
  else if (id < 1024) { W = sWo; K = 1024; N = 1024; t = id - 768;  doff = 3145728;  }
  else if (id < 2048) { W = sW1; K = 1024; N = 4096; t = id - 1024; doff = 4194304;  }
  else if (id < 6144) { W = sWg; K = 4096; N = 4096; t = id - 2048; doff = 8388608;  }
  else                { W = sW2; K = 4096; N = 1024; t = id - 6144; doff = 25165824; }
  unsigned short* WT = dstbase + doff;
  const int nx = N >> 6;
  const int n0 = (t % nx) * 64, k0 = (t / nx) * 64;

  __shared__ float tile[64][65];
  const int tr = threadIdx.x >> 4, tc = (threadIdx.x & 15) * 4;
#pragma unroll
  for (int i = 0; i < 4; ++i) {
    const float4 v = *(const float4*)&W[(size_t)(k0 + tr + i * 16) * N + n0 + tc];
    tile[tr + i * 16][tc + 0] = v.x;
    tile[tr + i * 16][tc + 1] = v.y;
    tile[tr + i * 16][tc + 2] = v.z;
    tile[tr + i * 16][tc + 3] = v.w;
  }
  __syncthreads();
#pragma unroll
  for (int i = 0; i < 4; ++i) {
    const int n = tr + i * 16;
    ushort4 o;
    o.x = f2bf(tile[tc + 0][n] * scale);
    o.y = f2bf(tile[tc + 1][n] * scale);
    o.z = f2bf(tile[tc + 2][n] * scale);
    o.w = f2bf(tile[tc + 3][n] * scale);
    *(ushort4*)&WT[(size_t)(n0 + n) * K + k0 + tc] = o;
  }
}

// ---------------------------------------------------------------------------
// kv_prep: K copy -> KP, V transpose -> VT (per (bh, 64-row s-chunk)).
// ---------------------------------------------------------------------------
__global__ __launch_bounds__(256)
void kv_prep(const unsigned short* __restrict__ qkv, unsigned short* __restrict__ KP,
             unsigned short* __restrict__ VT) {
  __shared__ unsigned short tile[128][66];
  const int bh = blockIdx.y, b = bh >> 3, h = bh & 7;
  const int s0 = blockIdx.x * 64;
  const size_t inbase = (size_t)b * 2048 * 3072 + h * 128;
  const int tr = threadIdx.x >> 4, tc = (threadIdx.x & 15) * 8;
#pragma unroll
  for (int i = 0; i < 4; ++i) {
    const int s = s0 + tr + i * 16;
    *(uint4*)&KP[((size_t)bh * 2048 + s) * 128 + tc] =
        *(const uint4*)&qkv[inbase + (size_t)s * 3072 + 1024 + tc];
  }
#pragma unroll
  for (int i = 0; i < 4; ++i) {
    const int r = tr + i * 16;
    const uint4 v = *(const uint4*)&qkv[inbase + (size_t)(s0 + r) * 3072 + 2048 + tc];
    const unsigned short* pv = (const unsigned short*)&v;
#pragma unroll
    for (int jj = 0; jj < 8; ++jj) tile[tc + jj][r] = pv[jj];
  }
  __syncthreads();
  const int e = threadIdx.x >> 1, sh = (threadIdx.x & 1) * 32;
#pragma unroll
  for (int i = 0; i < 4; ++i) {
    ushort4 o0, o1;
    o0.x = tile[e][sh + i * 8 + 0]; o0.y = tile[e][sh + i * 8 + 1];
    o0.z = tile[e][sh + i * 8 + 2]; o0.w = tile[e][sh + i * 8 + 3];
    o1.x = tile[e][sh + i * 8 + 4]; o1.y = tile[e][sh + i * 8 + 5];
    o1.z = tile[e][sh + i * 8 + 6]; o1.w = tile[e][sh + i * 8 + 7];
    *(ushort4*)&VT[((size_t)bh * 128 + e) * 2048 + s0 + sh + i * 8] = o0;
    *(ushort4*)&VT[((size_t)bh * 128 + e) * 2048 + s0 + sh + i * 8 + 4] = o1;
  }
}

// ---------------------------------------------------------------------------
// LayerNorm over rows of 1024 (bf16 out) — LN2.
// ---------------------------------------------------------------------------
__global__ __launch_bounds__(256)
void ln_kernel(const float* __restrict__ x, const float* __restrict__ g,
               const float* __restrict__ bsh, unsigned short* __restrict__ obf) {
  __shared__ float red[16];
  const int row = blockIdx.x, tid = threadIdx.x;
  const float4 v = *(const float4*)&x[(size_t)row * 1024 + tid * 4];
  float s = v.x + v.y + v.z + v.w;
  float q = v.x * v.x + v.y * v.y + v.z * v.z + v.w * v.w;
#pragma unroll
  for (int off = 32; off; off >>= 1) {
    s += __shfl_xor(s, off);
    q += __shfl_xor(q, off);
  }
  if ((tid & 63) == 0) {
    red[tid >> 6] = s;
    red[8 + (tid >> 6)] = q;
  }
  __syncthreads();
  s = red[0] + red[1] + red[2] + red[3];
  q = red[8] + red[9] + red[10] + red[11];
  const float mean = s * (1.f / 1024.f);
  const float var = q * (1.f / 1024.f) - mean * mean;
  const float rstd = rsqrtf(var + 1e-5f);
  const float4 gg = *(const float4*)&g[tid * 4];
  const float4 bb = *(const float4*)&bsh[tid * 4];
  ushort4 o;
  o.x = f2bf((v.x - mean) * rstd * gg.x + bb.x);
  o.y = f2bf((v.y - mean) * rstd * gg.y + bb.y);
  o.z = f2bf((v.z - mean) * rstd * gg.z + bb.z);
  o.w = f2bf((v.w - mean) * rstd * gg.w + bb.w);
  *(ushort4*)&obf[(size_t)row * 1024 + tid * 4] = o;
}

// ---------------------------------------------------------------------------
// GEMM 128x128, 4-wave, BK=64, deep pipeline (R15 staging schedule).
// ---------------------------------------------------------------------------
template <int EPI>
__global__ __launch_bounds__(256)
void gemm128(const unsigned short* __restrict__ A,
             const unsigned short* __restrict__ BT,
             const float* __restrict__ bias,
             const float* __restrict__ resf,
             const unsigned short* __restrict__ resb,
             void* __restrict__ Cout, int M, int N, int K, float bscale) {
  __shared__ unsigned short lds[32768];
  const int tid = threadIdx.x;
  const int w = tid >> 6, ln = tid & 63, lg = ln >> 4, lc = ln & 15;
  const int wm = w >> 1, wn = w & 1;
  const int nwg = gridDim.x * gridDim.y;
  const int linear = blockIdx.y * gridDim.x + blockIdx.x;
  const int swzb = (linear & 7) * (nwg >> 3) + (linear >> 3);
  const int m0 = (swzb / gridDim.x) * 128, n0 = (swzb % gridDim.x) * 128;

  f32x4 acc[4][4];
#pragma unroll
  for (int i = 0; i < 4; ++i)
#pragma unroll
    for (int j = 0; j < 4; ++j) acc[i][j] = (f32x4)0.f;

  auto stage_half = [&](int tensor, int j, int hh) {
    const unsigned short* base = tensor ? BT : A;
    const int row0 = (tensor ? n0 : m0) + hh * 64;
    const int slot = tensor * 4 + (j & 1) * 2 + hh;
#pragma unroll
    for (int c = 0; c < 2; ++c) {
      const int chunk = w * 2 + c;
      const int L = chunk * 1024 + ln * 16;
      const int r = L >> 7, inner = L & 127;
      const char* src = (const char*)(base + (size_t)(row0 + r) * K + j * 64) +
                        (inner ^ ((r & 7) << 4));
      __builtin_amdgcn_global_load_lds((GAS void*)src,
          (LAS void*)((char*)lds + slot * 8192 + chunk * 1024), 16, 0, 0);
    }
  };
  auto read_a = [&](int j, int mf, int ks) -> bf16x8 {
    const int r = mf * 16 + lc;
    const int slot = (j & 1) * 2 + wm;
    const int cb = ks * 64 + lg * 16;
    return *(const bf16x8*)((const char*)lds + slot * 8192 + r * 128 +
                            (cb ^ ((r & 7) << 4)));
  };
  auto read_b = [&](int j, int nf, int ks) -> bf16x8 {
    const int R = wn * 64 + nf * 16 + lc;
    const int slot = 4 + (j & 1) * 2 + (R >> 6);
    const int r = R & 63;
    const int cb = ks * 64 + lg * 16;
    return *(const bf16x8*)((const char*)lds + slot * 8192 + r * 128 +
                            (cb ^ ((r & 7) << 4)));
  };

  const int nkt = K / 64;

  stage_half(0, 0, 0); stage_half(0, 0, 1);
  stage_half(1, 0, 0); stage_half(1, 0, 1);
  stage_half(1, 1, 0); stage_half(1, 1, 1);
  asm volatile("s_waitcnt vmcnt(0)" ::: "memory");
  __builtin_amdgcn_s_barrier();

  bf16x8 bfr[4][2];
  for (int it = 0; it < nkt / 2; ++it) {
    const int J = it * 2;
#pragma unroll
    for (int half = 0; half < 2; ++half) {
      const int jc = J + half;
#pragma unroll
      for (int q = 0; q < 2; ++q) {
        if (q == 0) {
#pragma unroll
          for (int nf = 0; nf < 4; ++nf)
#pragma unroll
            for (int ks = 0; ks < 2; ++ks) bfr[nf][ks] = read_b(jc, nf, ks);
        }
        bf16x8 afr[2][2];
#pragma unroll
        for (int mm = 0; mm < 2; ++mm)
#pragma unroll
          for (int ks = 0; ks < 2; ++ks) afr[mm][ks] = read_a(jc, q * 2 + mm, ks);
        if (half == 0) {
          if (q == 0) { stage_half(0, J + 1, 0); stage_half(0, J + 1, 1); }
          else if (J + 2 < nkt) { stage_half(1, J + 2, 0); stage_half(1, J + 2, 1); }
        } else {
          if (q == 0) { if (J + 2 < nkt) { stage_half(0, J + 2, 0); stage_half(0, J + 2, 1); } }
          else if (J + 3 < nkt) { stage_half(1, J + 3, 0); stage_half(1, J + 3, 1); }
        }
        __builtin_amdgcn_s_barrier();
        asm volatile("s_waitcnt lgkmcnt(0)" ::: "memory");
        __builtin_amdgcn_sched_barrier(0);
        __builtin_amdgcn_s_setprio(1);
#pragma unroll
        for (int mm = 0; mm < 2; ++mm)
#pragma unroll
          for (int nf = 0; nf < 4; ++nf)
#pragma unroll
            for (int ks = 0; ks < 2; ++ks)
              acc[q * 2 + mm][nf] = __builtin_amdgcn_mfma_f32_16x16x32_bf16(
                  afr[mm][ks], bfr[nf][ks], acc[q * 2 + mm][nf], 0, 0, 0);
        __builtin_amdgcn_s_setprio(0);
        if (q == 1) {
          if ((half == 0 && J + 2 < nkt) || (half == 1 && J + 3 < nkt))
            asm volatile("s_waitcnt vmcnt(4)" ::: "memory");
          else
            asm volatile("s_waitcnt vmcnt(0)" ::: "memory");
        }
        __builtin_amdgcn_s_barrier();
      }
    }
  }

#pragma unroll
  for (int mf = 0; mf < 4; ++mf) {
#pragma unroll
    for (int nf = 0; nf < 4; ++nf) {
      const int c = n0 + wn * 64 + nf * 16 + lc;
      const float bc = bias[c] * bscale;
#pragma unroll
      for (int jj = 0; jj < 4; ++jj) {
        const int r = m0 + wm * 64 + mf * 16 + lg * 4 + jj;
        const size_t idx = (size_t)r * N + c;
        const float v = acc[mf][nf][jj] + bc;
        if (EPI == 1) {
          ((float*)Cout)[idx] = resf[idx] + v;
        } else if (EPI == 2) {
          ((float*)Cout)[idx] = bf2f(resb[idx]) + v;
        } else {
          ((unsigned short*)Cout)[idx] = f2bf(v);
        }
      }
    }
  }
}

// ---------------------------------------------------------------------------
// GEMM 256x256, 8-wave, BK=64, 8-phase deep pipeline (m201 template).
// ---------------------------------------------------------------------------
template <int EPI>
__global__ __launch_bounds__(512)
void gemm256(const unsigned short* __restrict__ A,
             const unsigned short* __restrict__ BT,
             const float* __restrict__ bias,
             const unsigned short* __restrict__ gate_u,
             unsigned short* __restrict__ Cout, int M, int N, int K) {
  __shared__ unsigned short lds[65536];
  const int tid = threadIdx.x;
  const int w = tid >> 6, ln = tid & 63, lg = ln >> 4, lc = ln & 15;
  const int wm = w >> 2, wn = w & 3;
  const int nwg = gridDim.x * gridDim.y;
  const int linear = blockIdx.y * gridDim.x + blockIdx.x;
  const int swzb = (linear & 7) * (nwg >> 3) + (linear >> 3);
  const int m0 = (swzb / gridDim.x) * 256, n0 = (swzb % gridDim.x) * 256;

  f32x4 acc[8][4];
#pragma unroll
  for (int i = 0; i < 8; ++i)
#pragma unroll
    for (int j = 0; j < 4; ++j) acc[i][j] = (f32x4)0.f;

  auto stage_half = [&](int tensor, int j, int hh) {
    const unsigned short* base = tensor ? BT : A;
    const int row0 = (tensor ? n0 : m0) + hh * 128;
    const int slot = tensor * 4 + (j & 1) * 2 + hh;
#pragma unroll
    for (int c = 0; c < 2; ++c) {
      const int chunk = w * 2 + c;
      const int L = chunk * 1024 + ln * 16;
      const int r = L >> 7, inner = L & 127;
      const char* src = (const char*)(base + (size_t)(row0 + r) * K + j * 64) +
                        (inner ^ ((r & 7) << 4));
      __builtin_amdgcn_global_load_lds((GAS void*)src,
          (LAS void*)((char*)lds + slot * 16384 + chunk * 1024), 16, 0, 0);
    }
  };
  auto read_a = [&](int j, int mf, int ks) -> bf16x8 {
    const int r = mf * 16 + lc;
    const int slot = (j & 1) * 2 + wm;
    const int cb = ks * 64 + lg * 16;
    return *(const bf16x8*)((const char*)lds + slot * 16384 + r * 128 +
                            (cb ^ ((r & 7) << 4)));
  };
  auto read_b = [&](int j, int nf, int ks) -> bf16x8 {
    const int R = wn * 64 + nf * 16 + lc;
    const int slot = 4 + (j & 1) * 2 + (R >> 7);
    const int r = R & 127;
    const int cb = ks * 64 + lg * 16;
    return *(const bf16x8*)((const char*)lds + slot * 16384 + r * 128 +
                            (cb ^ ((r & 7) << 4)));
  };

  const int nkt = K / 64;

  stage_half(0, 0, 0); stage_half(0, 0, 1);
  stage_half(1, 0, 0); stage_half(1, 0, 1);
  stage_half(1, 1, 0); stage_half(1, 1, 1);
  asm volatile("s_waitcnt vmcnt(0)" ::: "memory");
  __builtin_amdgcn_s_barrier();

  bf16x8 bfr[4][2];
  for (int it = 0; it < nkt / 2; ++it) {
    const int J = it * 2;
#pragma unroll
    for (int half = 0; half < 2; ++half) {
      const int jc = J + half;
#pragma unroll
      for (int q = 0; q < 4; ++q) {
        if (q == 0) {
#pragma unroll
          for (int nf = 0; nf < 4; ++nf)
#pragma unroll
            for (int ks = 0; ks < 2; ++ks) bfr[nf][ks] = read_b(jc, nf, ks);
        }
        bf16x8 afr[2][2];
#pragma unroll
        for (int mm = 0; mm < 2; ++mm)
#pragma unroll
          for (int ks = 0; ks < 2; ++ks) afr[mm][ks] = read_a(jc, q * 2 + mm, ks);
        if (half == 0) {
          if (q == 0) stage_half(0, J + 1, 0);
          if (q == 1) stage_half(0, J + 1, 1);
          if (q == 2 && J + 2 < nkt) stage_half(1, J + 2, 0);
          if (q == 3 && J + 2 < nkt) stage_half(1, J + 2, 1);
        } else {
          if (q == 0 && J + 2 < nkt) stage_half(0, J + 2, 0);
          if (q == 1 && J + 2 < nkt) stage_half(0, J + 2, 1);
          if (q == 2 && J + 3 < nkt) stage_half(1, J + 3, 0);
          if (q == 3 && J + 3 < nkt) stage_half(1, J + 3, 1);
        }
        __builtin_amdgcn_s_barrier();
        asm volatile("s_waitcnt lgkmcnt(0)" ::: "memory");
        __builtin_amdgcn_sched_barrier(0);
        __builtin_amdgcn_s_setprio(1);
#pragma unroll
        for (int mm = 0; mm < 2; ++mm)
#pragma unroll
          for (int nf = 0; nf < 4; ++nf)
#pragma unroll
            for (int ks = 0; ks < 2; ++ks)
              acc[q * 2 + mm][nf] = __builtin_amdgcn_mfma_f32_16x16x32_bf16(
                  afr[mm][ks], bfr[nf][ks], acc[q * 2 + mm][nf], 0, 0, 0);
        __builtin_amdgcn_s_setprio(0);
        if (q == 3) asm volatile("s_waitcnt vmcnt(4)" ::: "memory");
        __builtin_amdgcn_s_barrier();
      }
    }
  }

#pragma unroll
  for (int mf = 0; mf < 8; ++mf) {
#pragma unroll
    for (int nf = 0; nf < 4; ++nf) {
      const int c = n0 + wn * 64 + nf * 16 + lc;
      const float bc = bias[c];
#pragma unroll
      for (int jj = 0; jj < 4; ++jj) {
        const int r = m0 + wm * 128 + mf * 16 + lg * 4 + jj;
        const size_t idx = (size_t)r * N + c;
        const float v = acc[mf][nf][jj] + bc;
        if (EPI == 0) {
          Cout[idx] = f2bf(v);
        } else {
          const float uu = bf2f(gate_u[idx]);
          const float sw = v / (1.f + __expf(-v));   // silu
          Cout[idx] = f2bf(uu * sw);
        }
      }
    }
  }
}

// ---------------------------------------------------------------------------
// Differential attention, NT=1, fused lambda-diff + GroupNorm epilogue.
// exp2 trick: scores pre-scaled by log2e (in Wq/bq); P = exp2(S).
// ---------------------------------------------------------------------------
__global__ __launch_bounds__(256)
void attn_kernel(const unsigned short* __restrict__ q,
                 const unsigned short* __restrict__ KP,
                 const unsigned short* __restrict__ VT,
                 const float* __restrict__ lam,
                 const float* __restrict__ gn_w, const float* __restrict__ gn_b,
                 unsigned short* __restrict__ o) {
  constexpr int S = 2048;
  constexpr int QS = 3072;
  __shared__ unsigned short k_tile[2][32 * 128];
  __shared__ unsigned short v_tile[2][128 * 32];
  __shared__ unsigned short p_lds[4][2][512];
  const int tid = threadIdx.x, w = tid >> 6, ln = tid & 63, lg = ln >> 4, lc = ln & 15;
  const int id = blockIdx.x;
  const int bh = (id & 7) + 8 * ((id >> 8) & 1);
  const int qt = (id >> 3) & 31;
  const int h = bh & 7, b = bh >> 3;
  const size_t chan = (size_t)b * S * QS + h * 128;
  const size_t ochan = (size_t)b * S * 1024 + h * 128;
  const size_t kpbase = (size_t)bh * S * 128;
  const size_t vtbase = (size_t)bh * 128 * S;
  const int qrow = qt * 64 + w * 16 + lc;

  bf16x8 qf[2][2];
#pragma unroll
  for (int p = 0; p < 2; ++p)
#pragma unroll
    for (int ks = 0; ks < 2; ++ks)
      qf[p][ks] = *(const bf16x8*)&q[chan + (size_t)qrow * QS + p * 64 + ks * 32 + lg * 8];

  f32x4 O[2][8];
#pragma unroll
  for (int p = 0; p < 2; ++p)
#pragma unroll
    for (int ef = 0; ef < 8; ++ef) O[p][ef] = (f32x4)0.f;
  float lsum[2][4];
#pragma unroll
  for (int p = 0; p < 2; ++p)
#pragma unroll
    for (int j = 0; j < 4; ++j) lsum[p][j] = 0.f;

  const int prd = ((lc * 64 + lg * 16) ^ ((lc & 7) << 4)) >> 1;

  auto stage = [&](int buf, int t0) {
#pragma unroll
    for (int c = 0; c < 2; ++c) {
      {
        const int L = (w * 2 + c) * 1024 + ln * 16;
        const int r = L >> 8, inner = L & 255;
        const char* src = (const char*)(KP + kpbase + (size_t)(t0 + r) * 128) +
                          (inner ^ ((r & 7) << 4));
        __builtin_amdgcn_global_load_lds((GAS void*)src,
            (LAS void*)((char*)&k_tile[buf][0] + (w * 2 + c) * 1024), 16, 0, 0);
      }
      {
        const int L = (w * 2 + c) * 1024 + ln * 16;
        const int e = L >> 6, inner = L & 63;
        const char* src = (const char*)(VT + vtbase + (size_t)e * S + t0) +
                          (inner ^ ((e & 3) << 4));
        __builtin_amdgcn_global_load_lds((GAS void*)src,
            (LAS void*)((char*)&v_tile[buf][0] + (w * 2 + c) * 1024), 16, 0, 0);
      }
    }
  };

  auto compute = [&](int buf) {
    const char* kb = (const char*)&k_tile[buf][0];
    const char* vb = (const char*)&v_tile[buf][0];
#pragma unroll
    for (int p = 0; p < 2; ++p) {
      bf16x8 kf[2][2];
#pragma unroll
      for (int tf = 0; tf < 2; ++tf) {
        const int r = tf * 16 + lc;
#pragma unroll
        for (int ks = 0; ks < 2; ++ks)
          kf[tf][ks] = *(const bf16x8*)(kb + r * 256 +
                          ((p * 128 + ks * 64 + lg * 16) ^ ((r & 7) << 4)));
      }
      f32x4 sfr[2];
      __builtin_amdgcn_s_setprio(1);
#pragma unroll
      for (int tf = 0; tf < 2; ++tf) {
        f32x4 acc = (f32x4)0.f;
#pragma unroll
        for (int ks = 0; ks < 2; ++ks)
          acc = __builtin_amdgcn_mfma_f32_16x16x32_bf16(qf[p][ks], kf[tf][ks], acc, 0, 0, 0);
        sfr[tf] = acc;
      }
      __builtin_amdgcn_s_setprio(0);
#pragma unroll
      for (int tf = 0; tf < 2; ++tf)
#pragma unroll
        for (int j = 0; j < 4; ++j) {
          const float e = exp2f(sfr[tf][j]);
          lsum[p][j] += e;
          const int qq = lg * 4 + j;
          const int wi = ((qq * 64 + (tf * 16 + lc) * 2) ^ ((qq & 7) << 4)) >> 1;
          p_lds[w][p][wi] = f2bf(e);
        }
    }
    bf16x8 pa[2];
#pragma unroll
    for (int p = 0; p < 2; ++p)
      pa[p] = *(const bf16x8*)&p_lds[w][p][prd];
#pragma unroll
    for (int half = 0; half < 2; ++half) {
      bf16x8 vf[4];
#pragma unroll
      for (int ef = 0; ef < 4; ++ef) {
        const int e = (half * 4 + ef) * 16 + lc;
        vf[ef] = *(const bf16x8*)(vb + e * 64 + ((lg * 16) ^ ((e & 3) << 4)));
      }
      __builtin_amdgcn_s_setprio(1);
#pragma unroll
      for (int p = 0; p < 2; ++p)
#pragma unroll
        for (int ef = 0; ef < 4; ++ef)
          O[p][half * 4 + ef] = __builtin_amdgcn_mfma_f32_16x16x32_bf16(
              pa[p], vf[ef], O[p][half * 4 + ef], 0, 0, 0);
      __builtin_amdgcn_s_setprio(0);
    }
  };

  stage(0, 0);
  int cur = 0;
  for (int it = 0; it < 64; ++it) {
    if (it < 63) {
      stage(cur ^ 1, (it + 1) * 32);
      asm volatile("s_waitcnt vmcnt(4)" ::: "memory");
    } else {
      asm volatile("s_waitcnt vmcnt(0)" ::: "memory");
    }
    __builtin_amdgcn_s_barrier();
    compute(cur);
    __builtin_amdgcn_s_barrier();
    cur ^= 1;
  }

  // fused epilogue
#pragma unroll
  for (int p = 0; p < 2; ++p)
#pragma unroll
    for (int j = 0; j < 4; ++j) {
      float s = lsum[p][j];
      s += __shfl_xor(s, 1);
      s += __shfl_xor(s, 2);
      s += __shfl_xor(s, 4);
      s += __shfl_xor(s, 8);
      lsum[p][j] = s;
    }
  const float lamh = lam[h];
#pragma unroll
  for (int j = 0; j < 4; ++j) {
    const float inv1 = 1.f / lsum[0][j];
    const float inv2 = lamh / lsum[1][j];
    float dv[8], sum = 0.f, sq = 0.f;
#pragma unroll
    for (int ef = 0; ef < 8; ++ef) {
      dv[ef] = O[0][ef][j] * inv1 - O[1][ef][j] * inv2;
      sum += dv[ef];
      sq += dv[ef] * dv[ef];
    }
    sum += __shfl_xor(sum, 1); sq += __shfl_xor(sq, 1);
    sum += __shfl_xor(sum, 2); sq += __shfl_xor(sq, 2);
    sum += __shfl_xor(sum, 4); sq += __shfl_xor(sq, 4);
    sum += __shfl_xor(sum, 8); sq += __shfl_xor(sq, 8);
    const float mean = sum * (1.f / 128.f);
    const float var = sq * (1.f / 128.f) - mean * mean;
    const float rstd = rsqrtf(var + 1e-5f);
    const int row = qt * 64 + w * 16 + lg * 4 + j;
#pragma unroll
    for (int ef = 0; ef < 8; ++ef) {
      const int e = ef * 16 + lc;
      const float val = (dv[ef] - mean) * rstd * gn_w[h * 128 + e] + gn_b[h * 128 + e];
      o[ochan + (size_t)row * 1024 + e] = f2bf(val * 0.2f);
    }
  }
}

// ---------------------------------------------------------------------------
extern "C" void kernel_launch(void* const* d_in, const int* in_sizes, int n_in,
                              void* d_out, int out_size, void* d_ws, size_t ws_size,
                              hipStream_t stream) {
  (void)in_sizes; (void)n_in; (void)out_size; (void)ws_size;
  const float* x    = (const float*)d_in[0];
  const float* ln1g = (const float*)d_in[1];
  const float* ln1b = (const float*)d_in[2];
  const float* ln2g = (const float*)d_in[3];
  const float* ln2b = (const float*)d_in[4];
  const float* Wq   = (const float*)d_in[5];
  const float* bq   = (const float*)d_in[6];
  const float* Wk   = (const float*)d_in[7];
  const float* bk   = (const float*)d_in[8];
  const float* Wv   = (const float*)d_in[9];
  const float* bv   = (const float*)d_in[10];
  const float* Wo   = (const float*)d_in[11];
  const float* bo   = (const float*)d_in[12];
  const float* lq1  = (const float*)d_in[13];
  const float* lk1  = (const float*)d_in[14];
  const float* lq2  = (const float*)d_in[15];
  const float* lk2  = (const float*)d_in[16];
  const float* gnw  = (const float*)d_in[17];
  const float* gnb  = (const float*)d_in[18];
  const float* W1   = (const float*)d_in[19];
  const float* b1   = (const float*)d_in[20];
  const float* Wg   = (const float*)d_in[21];
  const float* bg   = (const float*)d_in[22];
  const float* W2   = (const float*)d_in[23];
  const float* b2   = (const float*)d_in[24];

  const int B = 2, S = 2048, D = 1024, F = 4096;
  const int M = B * S;  // 4096
  const float qscale = 0.125f * 1.4426950408889634f;   // 1/sqrt(64) * log2e

  char* ws = (char*)d_ws;
  size_t off = 0;
  auto alloc = [&](size_t bytes) {
    char* p = ws + off;
    off += (bytes + 255) & ~(size_t)255;
    return p;
  };
  unsigned short* WqkvT = (unsigned short*)alloc((size_t)3 * D * D * 2);
  unsigned short* WoT = (unsigned short*)alloc((size_t)D * D * 2);
  unsigned short* W1T = (unsigned short*)alloc((size_t)F * D * 2);
  unsigned short* WgT = (unsigned short*)alloc((size_t)F * F * 2);
  unsigned short* W2T = (unsigned short*)alloc((size_t)D * F * 2);
  float*          lamw= (float*)alloc(256);
  float*          bqkv= (float*)alloc(3072 * 4);
  unsigned short* h_bf= (unsigned short*)alloc((size_t)M * D * 2);
  unsigned short* qkv = (unsigned short*)alloc((size_t)M * 3 * D * 2);
  unsigned short* o_bf= (unsigned short*)alloc((size_t)M * D * 2);
  float*          x1  = (float*)alloc((size_t)M * D * 4);
  unsigned short* x2b = (unsigned short*)alloc((size_t)M * D * 2);
  unsigned short* u_bf= (unsigned short*)alloc((size_t)M * F * 2);
  unsigned short* w_bf= h_bf;   // gated act reuses h span

  unsigned short* KP = (unsigned short*)x1;
  unsigned short* VT = u_bf + (size_t)12 * 1024 * 1024;

  // --- fused prep: weights + bias + lambda + LN1 ---
  mega_prep<<<7181 + M, 256, 0, stream>>>(Wq, Wk, Wv, Wo, W1, Wg, W2, WqkvT,
                                          bq, bk, bv, bqkv,
                                          lq1, lk1, lq2, lk2, lamw,
                                          x, ln1g, ln1b, h_bf, qscale);

  // --- attention sublayer ---
  gemm256<0><<<dim3(3 * D / 256, M / 256), 512, 0, stream>>>(h_bf, WqkvT, bqkv, nullptr, qkv, M, 3 * D, D);
  kv_prep<<<dim3(S / 64, 16), 256, 0, stream>>>(qkv, KP, VT);
  attn_kernel<<<dim3(512), 256, 0, stream>>>(qkv, KP, VT, lamw, gnw, gnb, o_bf);
  gemm128<1><<<dim3(D / 128, M / 128), 256, 0, stream>>>(o_bf, WoT, bo, x, nullptr, x1, M, D, D, 1.0f);

  // --- FFN sublayer ---
  ln_kernel<<<M, 256, 0, stream>>>(x1, ln2g, ln2b, x2b);
  gemm256<0><<<dim3(F / 256, M / 256), 512, 0, stream>>>(x2b, W1T, b1, nullptr, u_bf, M, F, D);
  gemm256<2><<<dim3(F / 256, M / 256), 512, 0, stream>>>(u_bf, WgT, bg, u_bf, w_bf, M, F, F);
  gemm128<2><<<dim3(D / 128, M / 128), 256, 0, stream>>>(w_bf, W2T, b2, nullptr, x2b, (float*)d_out, M, D, F, 1.0f);
}

// Round 20
// 384.151 us; speedup vs baseline: 1.0470x; 1.0259x over previous
//
#include <hip/hip_runtime.h>
#include <hip/hip_bf16.h>

// ---------------------------------------------------------------------------
// EncoderBlock (differential attention + swiGLU FFN), MI355X / gfx950
// R19: attn KVBLK 32->64 — halves iteration count (64->32) to amortize the
//      per-iteration vmcnt+barrier stall over 2x compute. LDS 80KB
//      (K 2x16KB + V 2x16KB + P 16KB) = 2 blocks/CU (unchanged; grid-capped).
//      Stage = 8 loads/wave -> counted vmcnt(8). V/P rows now 128B with
//      ^( (row&7)<<4 ) swizzle; K rows unchanged (256B).
// ---------------------------------------------------------------------------

typedef __attribute__((ext_vector_type(8))) __bf16 bf16x8;
typedef __attribute__((ext_vector_type(4))) float f32x4;

#define GAS __attribute__((address_space(1)))
#define LAS __attribute__((address_space(3)))

__device__ __forceinline__ unsigned short f2bf(float f) {
  unsigned u = __float_as_uint(f);
  u += 0x7fffu + ((u >> 16) & 1u);   // RNE
  return (unsigned short)(u >> 16);
}
__device__ __forceinline__ float bf2f(unsigned short s) {
  return __uint_as_float(((unsigned)s) << 16);
}

// ---------------------------------------------------------------------------
// Mega-prep: [0,7168) weight transposes; [7168,7180) qkv bias; 7180 lambda;
// [7181, 7181+4096) LN1 rows.
// ---------------------------------------------------------------------------
__global__ __launch_bounds__(256)
void mega_prep(const float* __restrict__ sWq, const float* __restrict__ sWk,
               const float* __restrict__ sWv, const float* __restrict__ sWo,
               const float* __restrict__ sW1, const float* __restrict__ sWg,
               const float* __restrict__ sW2,
               unsigned short* __restrict__ dstbase,
               const float* __restrict__ bq, const float* __restrict__ bk,
               const float* __restrict__ bv, float* __restrict__ bqkv,
               const float* __restrict__ lq1, const float* __restrict__ lk1,
               const float* __restrict__ lq2, const float* __restrict__ lk2,
               float* __restrict__ lam,
               const float* __restrict__ x, const float* __restrict__ ln1g,
               const float* __restrict__ ln1b, unsigned short* __restrict__ h_bf,
               float qscale) {
  const int id = blockIdx.x;
  if (id >= 7181) {   // LN1 over row (id-7181)
    __shared__ float red[16];
    const int row = id - 7181, tid = threadIdx.x;
    const float4 v = *(const float4*)&x[(size_t)row * 1024 + tid * 4];
    float s = v.x + v.y + v.z + v.w;
    float q = v.x * v.x + v.y * v.y + v.z * v.z + v.w * v.w;
#pragma unroll
    for (int off = 32; off; off >>= 1) {
      s += __shfl_xor(s, off);
      q += __shfl_xor(q, off);
    }
    if ((tid & 63) == 0) { red[tid >> 6] = s; red[8 + (tid >> 6)] = q; }
    __syncthreads();
    s = red[0] + red[1] + red[2] + red[3];
    q = red[8] + red[9] + red[10] + red[11];
    const float mean = s * (1.f / 1024.f);
    const float var = q * (1.f / 1024.f) - mean * mean;
    const float rstd = rsqrtf(var + 1e-5f);
    const float4 gg = *(const float4*)&ln1g[tid * 4];
    const float4 bb = *(const float4*)&ln1b[tid * 4];
    ushort4 o;
    o.x = f2bf((v.x - mean) * rstd * gg.x + bb.x);
    o.y = f2bf((v.y - mean) * rstd * gg.y + bb.y);
    o.z = f2bf((v.z - mean) * rstd * gg.z + bb.z);
    o.w = f2bf((v.w - mean) * rstd * gg.w + bb.w);
    *(ushort4*)&h_bf[(size_t)row * 1024 + tid * 4] = o;
    return;
  }
  if (id == 7180) {   // lambda: 8 heads x 32 lanes, 2 dims/lane
    const int hh = threadIdx.x >> 5, d = (threadIdx.x & 31) * 2;
    float a = lq1[hh * 64 + d] * lk1[hh * 64 + d] + lq1[hh * 64 + d + 1] * lk1[hh * 64 + d + 1];
    float c = lq2[hh * 64 + d] * lk2[hh * 64 + d] + lq2[hh * 64 + d + 1] * lk2[hh * 64 + d + 1];
#pragma unroll
    for (int off = 16; off; off >>= 1) {
      a += __shfl_xor(a, off);
      c += __shfl_xor(c, off);
    }
    if ((threadIdx.x & 31) == 0) lam[hh] = __expf(a) - __expf(c) + 0.8f;
    return;
  }
  if (id >= 7168) {   // qkv bias
    const int i = (id - 7168) * 256 + threadIdx.x;
    if (i < 1024) bqkv[i] = bq[i] * qscale;
    else if (i < 2048) bqkv[i] = bk[i - 1024];
    else bqkv[i] = bv[i - 2048];
    return;
  }
  const float* W;
  int K, N, t;
  size_t doff;
  float scale = 1.0f;
  if (id < 256)       { W = sWq; K = 1024; N = 1024; t = id;        doff = 0;        scale = qscale; }
  else if (id < 512)  { W = sWk; K = 1024; N = 1024; t = id - 256;  doff = 1048576;  }
  else if (id < 768)  { W = sWv; K = 1024; N = 1024; t = id - 512;  doff = 2097152;  }
  else if (id < 1024) { W = sWo; K = 1024; N = 1024; t = id - 768;  doff = 3145728;  }
  else if (id < 2048) { W = sW1; K = 1024; N = 4096; t = id - 1024; doff = 4194304;  }
  else if (id < 6144) { W = sWg; K = 4096; N = 4096; t = id - 2048; doff = 8388608;  }
  else                { W = sW2; K = 4096; N = 1024; t = id - 6144; doff = 25165824; }
  unsigned short* WT = dstbase + doff;
  const int nx = N >> 6;
  const int n0 = (t % nx) * 64, k0 = (t / nx) * 64;

  __shared__ float tile[64][65];
  const int tr = threadIdx.x >> 4, tc = (threadIdx.x & 15) * 4;
#pragma unroll
  for (int i = 0; i < 4; ++i) {
    const float4 v = *(const float4*)&W[(size_t)(k0 + tr + i * 16) * N + n0 + tc];
    tile[tr + i * 16][tc + 0] = v.x;
    tile[tr + i * 16][tc + 1] = v.y;
    tile[tr + i * 16][tc + 2] = v.z;
    tile[tr + i * 16][tc + 3] = v.w;
  }
  __syncthreads();
#pragma unroll
  for (int i = 0; i < 4; ++i) {
    const int n = tr + i * 16;
    ushort4 o;
    o.x = f2bf(tile[tc + 0][n] * scale);
    o.y = f2bf(tile[tc + 1][n] * scale);
    o.z = f2bf(tile[tc + 2][n] * scale);
    o.w = f2bf(tile[tc + 3][n] * scale);
    *(ushort4*)&WT[(size_t)(n0 + n) * K + k0 + tc] = o;
  }
}

// ---------------------------------------------------------------------------
// kv_prep: K copy -> KP, V transpose -> VT (per (bh, 64-row s-chunk)).
// ---------------------------------------------------------------------------
__global__ __launch_bounds__(256)
void kv_prep(const unsigned short* __restrict__ qkv, unsigned short* __restrict__ KP,
             unsigned short* __restrict__ VT) {
  __shared__ unsigned short tile[128][66];
  const int bh = blockIdx.y, b = bh >> 3, h = bh & 7;
  const int s0 = blockIdx.x * 64;
  const size_t inbase = (size_t)b * 2048 * 3072 + h * 128;
  const int tr = threadIdx.x >> 4, tc = (threadIdx.x & 15) * 8;
#pragma unroll
  for (int i = 0; i < 4; ++i) {
    const int s = s0 + tr + i * 16;
    *(uint4*)&KP[((size_t)bh * 2048 + s) * 128 + tc] =
        *(const uint4*)&qkv[inbase + (size_t)s * 3072 + 1024 + tc];
  }
#pragma unroll
  for (int i = 0; i < 4; ++i) {
    const int r = tr + i * 16;
    const uint4 v = *(const uint4*)&qkv[inbase + (size_t)(s0 + r) * 3072 + 2048 + tc];
    const unsigned short* pv = (const unsigned short*)&v;
#pragma unroll
    for (int jj = 0; jj < 8; ++jj) tile[tc + jj][r] = pv[jj];
  }
  __syncthreads();
  const int e = threadIdx.x >> 1, sh = (threadIdx.x & 1) * 32;
#pragma unroll
  for (int i = 0; i < 4; ++i) {
    ushort4 o0, o1;
    o0.x = tile[e][sh + i * 8 + 0]; o0.y = tile[e][sh + i * 8 + 1];
    o0.z = tile[e][sh + i * 8 + 2]; o0.w = tile[e][sh + i * 8 + 3];
    o1.x = tile[e][sh + i * 8 + 4]; o1.y = tile[e][sh + i * 8 + 5];
    o1.z = tile[e][sh + i * 8 + 6]; o1.w = tile[e][sh + i * 8 + 7];
    *(ushort4*)&VT[((size_t)bh * 128 + e) * 2048 + s0 + sh + i * 8] = o0;
    *(ushort4*)&VT[((size_t)bh * 128 + e) * 2048 + s0 + sh + i * 8 + 4] = o1;
  }
}

// ---------------------------------------------------------------------------
// LayerNorm over rows of 1024 (bf16 out) — LN2.
// ---------------------------------------------------------------------------
__global__ __launch_bounds__(256)
void ln_kernel(const float* __restrict__ x, const float* __restrict__ g,
               const float* __restrict__ bsh, unsigned short* __restrict__ obf) {
  __shared__ float red[16];
  const int row = blockIdx.x, tid = threadIdx.x;
  const float4 v = *(const float4*)&x[(size_t)row * 1024 + tid * 4];
  float s = v.x + v.y + v.z + v.w;
  float q = v.x * v.x + v.y * v.y + v.z * v.z + v.w * v.w;
#pragma unroll
  for (int off = 32; off; off >>= 1) {
    s += __shfl_xor(s, off);
    q += __shfl_xor(q, off);
  }
  if ((tid & 63) == 0) {
    red[tid >> 6] = s;
    red[8 + (tid >> 6)] = q;
  }
  __syncthreads();
  s = red[0] + red[1] + red[2] + red[3];
  q = red[8] + red[9] + red[10] + red[11];
  const float mean = s * (1.f / 1024.f);
  const float var = q * (1.f / 1024.f) - mean * mean;
  const float rstd = rsqrtf(var + 1e-5f);
  const float4 gg = *(const float4*)&g[tid * 4];
  const float4 bb = *(const float4*)&bsh[tid * 4];
  ushort4 o;
  o.x = f2bf((v.x - mean) * rstd * gg.x + bb.x);
  o.y = f2bf((v.y - mean) * rstd * gg.y + bb.y);
  o.z = f2bf((v.z - mean) * rstd * gg.z + bb.z);
  o.w = f2bf((v.w - mean) * rstd * gg.w + bb.w);
  *(ushort4*)&obf[(size_t)row * 1024 + tid * 4] = o;
}

// ---------------------------------------------------------------------------
// GEMM 128x128, 4-wave, BK=64, deep pipeline (R15 staging schedule).
// ---------------------------------------------------------------------------
template <int EPI>
__global__ __launch_bounds__(256)
void gemm128(const unsigned short* __restrict__ A,
             const unsigned short* __restrict__ BT,
             const float* __restrict__ bias,
             const float* __restrict__ resf,
             const unsigned short* __restrict__ resb,
             void* __restrict__ Cout, int M, int N, int K, float bscale) {
  __shared__ unsigned short lds[32768];
  const int tid = threadIdx.x;
  const int w = tid >> 6, ln = tid & 63, lg = ln >> 4, lc = ln & 15;
  const int wm = w >> 1, wn = w & 1;
  const int nwg = gridDim.x * gridDim.y;
  const int linear = blockIdx.y * gridDim.x + blockIdx.x;
  const int swzb = (linear & 7) * (nwg >> 3) + (linear >> 3);
  const int m0 = (swzb / gridDim.x) * 128, n0 = (swzb % gridDim.x) * 128;

  f32x4 acc[4][4];
#pragma unroll
  for (int i = 0; i < 4; ++i)
#pragma unroll
    for (int j = 0; j < 4; ++j) acc[i][j] = (f32x4)0.f;

  auto stage_half = [&](int tensor, int j, int hh) {
    const unsigned short* base = tensor ? BT : A;
    const int row0 = (tensor ? n0 : m0) + hh * 64;
    const int slot = tensor * 4 + (j & 1) * 2 + hh;
#pragma unroll
    for (int c = 0; c < 2; ++c) {
      const int chunk = w * 2 + c;
      const int L = chunk * 1024 + ln * 16;
      const int r = L >> 7, inner = L & 127;
      const char* src = (const char*)(base + (size_t)(row0 + r) * K + j * 64) +
                        (inner ^ ((r & 7) << 4));
      __builtin_amdgcn_global_load_lds((GAS void*)src,
          (LAS void*)((char*)lds + slot * 8192 + chunk * 1024), 16, 0, 0);
    }
  };
  auto read_a = [&](int j, int mf, int ks) -> bf16x8 {
    const int r = mf * 16 + lc;
    const int slot = (j & 1) * 2 + wm;
    const int cb = ks * 64 + lg * 16;
    return *(const bf16x8*)((const char*)lds + slot * 8192 + r * 128 +
                            (cb ^ ((r & 7) << 4)));
  };
  auto read_b = [&](int j, int nf, int ks) -> bf16x8 {
    const int R = wn * 64 + nf * 16 + lc;
    const int slot = 4 + (j & 1) * 2 + (R >> 6);
    const int r = R & 63;
    const int cb = ks * 64 + lg * 16;
    return *(const bf16x8*)((const char*)lds + slot * 8192 + r * 128 +
                            (cb ^ ((r & 7) << 4)));
  };

  const int nkt = K / 64;

  stage_half(0, 0, 0); stage_half(0, 0, 1);
  stage_half(1, 0, 0); stage_half(1, 0, 1);
  stage_half(1, 1, 0); stage_half(1, 1, 1);
  asm volatile("s_waitcnt vmcnt(0)" ::: "memory");
  __builtin_amdgcn_s_barrier();

  bf16x8 bfr[4][2];
  for (int it = 0; it < nkt / 2; ++it) {
    const int J = it * 2;
#pragma unroll
    for (int half = 0; half < 2; ++half) {
      const int jc = J + half;
#pragma unroll
      for (int q = 0; q < 2; ++q) {
        if (q == 0) {
#pragma unroll
          for (int nf = 0; nf < 4; ++nf)
#pragma unroll
            for (int ks = 0; ks < 2; ++ks) bfr[nf][ks] = read_b(jc, nf, ks);
        }
        bf16x8 afr[2][2];
#pragma unroll
        for (int mm = 0; mm < 2; ++mm)
#pragma unroll
          for (int ks = 0; ks < 2; ++ks) afr[mm][ks] = read_a(jc, q * 2 + mm, ks);
        if (half == 0) {
          if (q == 0) { stage_half(0, J + 1, 0); stage_half(0, J + 1, 1); }
          else if (J + 2 < nkt) { stage_half(1, J + 2, 0); stage_half(1, J + 2, 1); }
        } else {
          if (q == 0) { if (J + 2 < nkt) { stage_half(0, J + 2, 0); stage_half(0, J + 2, 1); } }
          else if (J + 3 < nkt) { stage_half(1, J + 3, 0); stage_half(1, J + 3, 1); }
        }
        __builtin_amdgcn_s_barrier();
        asm volatile("s_waitcnt lgkmcnt(0)" ::: "memory");
        __builtin_amdgcn_sched_barrier(0);
        __builtin_amdgcn_s_setprio(1);
#pragma unroll
        for (int mm = 0; mm < 2; ++mm)
#pragma unroll
          for (int nf = 0; nf < 4; ++nf)
#pragma unroll
            for (int ks = 0; ks < 2; ++ks)
              acc[q * 2 + mm][nf] = __builtin_amdgcn_mfma_f32_16x16x32_bf16(
                  afr[mm][ks], bfr[nf][ks], acc[q * 2 + mm][nf], 0, 0, 0);
        __builtin_amdgcn_s_setprio(0);
        if (q == 1) {
          if ((half == 0 && J + 2 < nkt) || (half == 1 && J + 3 < nkt))
            asm volatile("s_waitcnt vmcnt(4)" ::: "memory");
          else
            asm volatile("s_waitcnt vmcnt(0)" ::: "memory");
        }
        __builtin_amdgcn_s_barrier();
      }
    }
  }

#pragma unroll
  for (int mf = 0; mf < 4; ++mf) {
#pragma unroll
    for (int nf = 0; nf < 4; ++nf) {
      const int c = n0 + wn * 64 + nf * 16 + lc;
      const float bc = bias[c] * bscale;
#pragma unroll
      for (int jj = 0; jj < 4; ++jj) {
        const int r = m0 + wm * 64 + mf * 16 + lg * 4 + jj;
        const size_t idx = (size_t)r * N + c;
        const float v = acc[mf][nf][jj] + bc;
        if (EPI == 1) {
          ((float*)Cout)[idx] = resf[idx] + v;
        } else if (EPI == 2) {
          ((float*)Cout)[idx] = bf2f(resb[idx]) + v;
        } else {
          ((unsigned short*)Cout)[idx] = f2bf(v);
        }
      }
    }
  }
}

// ---------------------------------------------------------------------------
// GEMM 256x256, 8-wave, BK=64, 8-phase deep pipeline (m201 template).
// ---------------------------------------------------------------------------
template <int EPI>
__global__ __launch_bounds__(512)
void gemm256(const unsigned short* __restrict__ A,
             const unsigned short* __restrict__ BT,
             const float* __restrict__ bias,
             const unsigned short* __restrict__ gate_u,
             unsigned short* __restrict__ Cout, int M, int N, int K) {
  __shared__ unsigned short lds[65536];
  const int tid = threadIdx.x;
  const int w = tid >> 6, ln = tid & 63, lg = ln >> 4, lc = ln & 15;
  const int wm = w >> 2, wn = w & 3;
  const int nwg = gridDim.x * gridDim.y;
  const int linear = blockIdx.y * gridDim.x + blockIdx.x;
  const int swzb = (linear & 7) * (nwg >> 3) + (linear >> 3);
  const int m0 = (swzb / gridDim.x) * 256, n0 = (swzb % gridDim.x) * 256;

  f32x4 acc[8][4];
#pragma unroll
  for (int i = 0; i < 8; ++i)
#pragma unroll
    for (int j = 0; j < 4; ++j) acc[i][j] = (f32x4)0.f;

  auto stage_half = [&](int tensor, int j, int hh) {
    const unsigned short* base = tensor ? BT : A;
    const int row0 = (tensor ? n0 : m0) + hh * 128;
    const int slot = tensor * 4 + (j & 1) * 2 + hh;
#pragma unroll
    for (int c = 0; c < 2; ++c) {
      const int chunk = w * 2 + c;
      const int L = chunk * 1024 + ln * 16;
      const int r = L >> 7, inner = L & 127;
      const char* src = (const char*)(base + (size_t)(row0 + r) * K + j * 64) +
                        (inner ^ ((r & 7) << 4));
      __builtin_amdgcn_global_load_lds((GAS void*)src,
          (LAS void*)((char*)lds + slot * 16384 + chunk * 1024), 16, 0, 0);
    }
  };
  auto read_a = [&](int j, int mf, int ks) -> bf16x8 {
    const int r = mf * 16 + lc;
    const int slot = (j & 1) * 2 + wm;
    const int cb = ks * 64 + lg * 16;
    return *(const bf16x8*)((const char*)lds + slot * 16384 + r * 128 +
                            (cb ^ ((r & 7) << 4)));
  };
  auto read_b = [&](int j, int nf, int ks) -> bf16x8 {
    const int R = wn * 64 + nf * 16 + lc;
    const int slot = 4 + (j & 1) * 2 + (R >> 7);
    const int r = R & 127;
    const int cb = ks * 64 + lg * 16;
    return *(const bf16x8*)((const char*)lds + slot * 16384 + r * 128 +
                            (cb ^ ((r & 7) << 4)));
  };

  const int nkt = K / 64;

  stage_half(0, 0, 0); stage_half(0, 0, 1);
  stage_half(1, 0, 0); stage_half(1, 0, 1);
  stage_half(1, 1, 0); stage_half(1, 1, 1);
  asm volatile("s_waitcnt vmcnt(0)" ::: "memory");
  __builtin_amdgcn_s_barrier();

  bf16x8 bfr[4][2];
  for (int it = 0; it < nkt / 2; ++it) {
    const int J = it * 2;
#pragma unroll
    for (int half = 0; half < 2; ++half) {
      const int jc = J + half;
#pragma unroll
      for (int q = 0; q < 4; ++q) {
        if (q == 0) {
#pragma unroll
          for (int nf = 0; nf < 4; ++nf)
#pragma unroll
            for (int ks = 0; ks < 2; ++ks) bfr[nf][ks] = read_b(jc, nf, ks);
        }
        bf16x8 afr[2][2];
#pragma unroll
        for (int mm = 0; mm < 2; ++mm)
#pragma unroll
          for (int ks = 0; ks < 2; ++ks) afr[mm][ks] = read_a(jc, q * 2 + mm, ks);
        if (half == 0) {
          if (q == 0) stage_half(0, J + 1, 0);
          if (q == 1) stage_half(0, J + 1, 1);
          if (q == 2 && J + 2 < nkt) stage_half(1, J + 2, 0);
          if (q == 3 && J + 2 < nkt) stage_half(1, J + 2, 1);
        } else {
          if (q == 0 && J + 2 < nkt) stage_half(0, J + 2, 0);
          if (q == 1 && J + 2 < nkt) stage_half(0, J + 2, 1);
          if (q == 2 && J + 3 < nkt) stage_half(1, J + 3, 0);
          if (q == 3 && J + 3 < nkt) stage_half(1, J + 3, 1);
        }
        __builtin_amdgcn_s_barrier();
        asm volatile("s_waitcnt lgkmcnt(0)" ::: "memory");
        __builtin_amdgcn_sched_barrier(0);
        __builtin_amdgcn_s_setprio(1);
#pragma unroll
        for (int mm = 0; mm < 2; ++mm)
#pragma unroll
          for (int nf = 0; nf < 4; ++nf)
#pragma unroll
            for (int ks = 0; ks < 2; ++ks)
              acc[q * 2 + mm][nf] = __builtin_amdgcn_mfma_f32_16x16x32_bf16(
                  afr[mm][ks], bfr[nf][ks], acc[q * 2 + mm][nf], 0, 0, 0);
        __builtin_amdgcn_s_setprio(0);
        if (q == 3) asm volatile("s_waitcnt vmcnt(4)" ::: "memory");
        __builtin_amdgcn_s_barrier();
      }
    }
  }

#pragma unroll
  for (int mf = 0; mf < 8; ++mf) {
#pragma unroll
    for (int nf = 0; nf < 4; ++nf) {
      const int c = n0 + wn * 64 + nf * 16 + lc;
      const float bc = bias[c];
#pragma unroll
      for (int jj = 0; jj < 4; ++jj) {
        const int r = m0 + wm * 128 + mf * 16 + lg * 4 + jj;
        const size_t idx = (size_t)r * N + c;
        const float v = acc[mf][nf][jj] + bc;
        if (EPI == 0) {
          Cout[idx] = f2bf(v);
        } else {
          const float uu = bf2f(gate_u[idx]);
          const float sw = v / (1.f + __expf(-v));   // silu
          Cout[idx] = f2bf(uu * sw);
        }
      }
    }
  }
}

// ---------------------------------------------------------------------------
// Differential attention, NT=1, KVBLK=64, fused lambda-diff + GroupNorm.
// LDS: K 2x16KB + V 2x16KB + P 16KB = 80KB. Stage 8 loads/wave, vmcnt(8).
// ---------------------------------------------------------------------------
__global__ __launch_bounds__(256)
void attn_kernel(const unsigned short* __restrict__ q,
                 const unsigned short* __restrict__ KP,
                 const unsigned short* __restrict__ VT,
                 const float* __restrict__ lam,
                 const float* __restrict__ gn_w, const float* __restrict__ gn_b,
                 unsigned short* __restrict__ o) {
  constexpr int S = 2048;
  constexpr int QS = 3072;
  __shared__ unsigned short k_tile[2][64 * 128];   // [t=64][d=128] swz (r&7)<<4
  __shared__ unsigned short v_tile[2][128 * 64];   // [e=128][t=64] swz (e&7)<<4
  __shared__ unsigned short p_lds[4][2][1024];     // [wave][pair][16q x 64t] swz (q&7)<<4
  const int tid = threadIdx.x, w = tid >> 6, ln = tid & 63, lg = ln >> 4, lc = ln & 15;
  const int id = blockIdx.x;
  const int bh = (id & 7) + 8 * ((id >> 8) & 1);
  const int qt = (id >> 3) & 31;
  const int h = bh & 7, b = bh >> 3;
  const size_t chan = (size_t)b * S * QS + h * 128;
  const size_t ochan = (size_t)b * S * 1024 + h * 128;
  const size_t kpbase = (size_t)bh * S * 128;
  const size_t vtbase = (size_t)bh * 128 * S;
  const int qrow = qt * 64 + w * 16 + lc;

  bf16x8 qf[2][2];
#pragma unroll
  for (int p = 0; p < 2; ++p)
#pragma unroll
    for (int ks = 0; ks < 2; ++ks)
      qf[p][ks] = *(const bf16x8*)&q[chan + (size_t)qrow * QS + p * 64 + ks * 32 + lg * 8];

  f32x4 O[2][8];
#pragma unroll
  for (int p = 0; p < 2; ++p)
#pragma unroll
    for (int ef = 0; ef < 8; ++ef) O[p][ef] = (f32x4)0.f;
  float lsum[2][4];
#pragma unroll
  for (int p = 0; p < 2; ++p)
#pragma unroll
    for (int j = 0; j < 4; ++j) lsum[p][j] = 0.f;

  auto stage = [&](int buf, int t0) {
#pragma unroll
    for (int c = 0; c < 4; ++c) {
      const int chunk = w * 4 + c;          // 0..15, 1KB each
      const int L = chunk * 1024 + ln * 16;
      {
        // K: 64 rows x 256B
        const int r = L >> 8, inner = L & 255;
        const char* src = (const char*)(KP + kpbase + (size_t)(t0 + r) * 128) +
                          (inner ^ ((r & 7) << 4));
        __builtin_amdgcn_global_load_lds((GAS void*)src,
            (LAS void*)((char*)&k_tile[buf][0] + chunk * 1024), 16, 0, 0);
      }
      {
        // V: 128 rows x 128B
        const int e = L >> 7, inner = L & 127;
        const char* src = (const char*)(VT + vtbase + (size_t)e * S + t0) +
                          (inner ^ ((e & 7) << 4));
        __builtin_amdgcn_global_load_lds((GAS void*)src,
            (LAS void*)((char*)&v_tile[buf][0] + chunk * 1024), 16, 0, 0);
      }
    }
  };

  auto compute = [&](int buf) {
    const char* kb = (const char*)&k_tile[buf][0];
    const char* vb = (const char*)&v_tile[buf][0];
    char* pb = (char*)&p_lds[w][0][0];
    // QK^T + exp2 + P-write, both pairs, 4 t-fragments
#pragma unroll
    for (int p = 0; p < 2; ++p) {
      f32x4 sfr[4];
#pragma unroll
      for (int tf = 0; tf < 4; ++tf) {
        const int r = tf * 16 + lc;
        bf16x8 kf0 = *(const bf16x8*)(kb + r * 256 +
                        ((p * 128 + 0 * 64 + lg * 16) ^ ((r & 7) << 4)));
        bf16x8 kf1 = *(const bf16x8*)(kb + r * 256 +
                        ((p * 128 + 1 * 64 + lg * 16) ^ ((r & 7) << 4)));
        __builtin_amdgcn_s_setprio(1);
        f32x4 acc = (f32x4)0.f;
        acc = __builtin_amdgcn_mfma_f32_16x16x32_bf16(qf[p][0], kf0, acc, 0, 0, 0);
        acc = __builtin_amdgcn_mfma_f32_16x16x32_bf16(qf[p][1], kf1, acc, 0, 0, 0);
        __builtin_amdgcn_s_setprio(0);
        sfr[tf] = acc;
      }
#pragma unroll
      for (int tf = 0; tf < 4; ++tf)
#pragma unroll
        for (int j = 0; j < 4; ++j) {
          const float e = exp2f(sfr[tf][j]);
          lsum[p][j] += e;
          const int qq = lg * 4 + j;
          const int byteoff = (qq * 128 + (tf * 16 + lc) * 2) ^ ((qq & 7) << 4);
          *(unsigned short*)(pb + p * 2048 + byteoff) = f2bf(e);
        }
    }
    // PV: 2 ksv x (pa[2] + 2 halves of vf[4])
#pragma unroll
    for (int ksv = 0; ksv < 2; ++ksv) {
      bf16x8 pa[2];
#pragma unroll
      for (int p = 0; p < 2; ++p)
        pa[p] = *(const bf16x8*)(pb + p * 2048 + (lc * 128 +
                    ((ksv * 64 + lg * 16) ^ ((lc & 7) << 4))));
#pragma unroll
      for (int half = 0; half < 2; ++half) {
        bf16x8 vf[4];
#pragma unroll
        for (int ef = 0; ef < 4; ++ef) {
          const int e = (half * 4 + ef) * 16 + lc;
          vf[ef] = *(const bf16x8*)(vb + e * 128 +
                      ((ksv * 64 + lg * 16) ^ ((e & 7) << 4)));
        }
        __builtin_amdgcn_s_setprio(1);
#pragma unroll
        for (int p = 0; p < 2; ++p)
#pragma unroll
          for (int ef = 0; ef < 4; ++ef)
            O[p][half * 4 + ef] = __builtin_amdgcn_mfma_f32_16x16x32_bf16(
                pa[p], vf[ef], O[p][half * 4 + ef], 0, 0, 0);
        __builtin_amdgcn_s_setprio(0);
      }
    }
  };

  stage(0, 0);
  int cur = 0;
  for (int it = 0; it < 32; ++it) {
    if (it < 31) {
      stage(cur ^ 1, (it + 1) * 64);
      asm volatile("s_waitcnt vmcnt(8)" ::: "memory");
    } else {
      asm volatile("s_waitcnt vmcnt(0)" ::: "memory");
    }
    __builtin_amdgcn_s_barrier();
    compute(cur);
    __builtin_amdgcn_s_barrier();
    cur ^= 1;
  }

  // fused epilogue
#pragma unroll
  for (int p = 0; p < 2; ++p)
#pragma unroll
    for (int j = 0; j < 4; ++j) {
      float s = lsum[p][j];
      s += __shfl_xor(s, 1);
      s += __shfl_xor(s, 2);
      s += __shfl_xor(s, 4);
      s += __shfl_xor(s, 8);
      lsum[p][j] = s;
    }
  const float lamh = lam[h];
#pragma unroll
  for (int j = 0; j < 4; ++j) {
    const float inv1 = 1.f / lsum[0][j];
    const float inv2 = lamh / lsum[1][j];
    float dv[8], sum = 0.f, sq = 0.f;
#pragma unroll
    for (int ef = 0; ef < 8; ++ef) {
      dv[ef] = O[0][ef][j] * inv1 - O[1][ef][j] * inv2;
      sum += dv[ef];
      sq += dv[ef] * dv[ef];
    }
    sum += __shfl_xor(sum, 1); sq += __shfl_xor(sq, 1);
    sum += __shfl_xor(sum, 2); sq += __shfl_xor(sq, 2);
    sum += __shfl_xor(sum, 4); sq += __shfl_xor(sq, 4);
    sum += __shfl_xor(sum, 8); sq += __shfl_xor(sq, 8);
    const float mean = sum * (1.f / 128.f);
    const float var = sq * (1.f / 128.f) - mean * mean;
    const float rstd = rsqrtf(var + 1e-5f);
    const int row = qt * 64 + w * 16 + lg * 4 + j;
#pragma unroll
    for (int ef = 0; ef < 8; ++ef) {
      const int e = ef * 16 + lc;
      const float val = (dv[ef] - mean) * rstd * gn_w[h * 128 + e] + gn_b[h * 128 + e];
      o[ochan + (size_t)row * 1024 + e] = f2bf(val * 0.2f);
    }
  }
}

// ---------------------------------------------------------------------------
extern "C" void kernel_launch(void* const* d_in, const int* in_sizes, int n_in,
                              void* d_out, int out_size, void* d_ws, size_t ws_size,
                              hipStream_t stream) {
  (void)in_sizes; (void)n_in; (void)out_size; (void)ws_size;
  const float* x    = (const float*)d_in[0];
  const float* ln1g = (const float*)d_in[1];
  const float* ln1b = (const float*)d_in[2];
  const float* ln2g = (const float*)d_in[3];
  const float* ln2b = (const float*)d_in[4];
  const float* Wq   = (const float*)d_in[5];
  const float* bq   = (const float*)d_in[6];
  const float* Wk   = (const float*)d_in[7];
  const float* bk   = (const float*)d_in[8];
  const float* Wv   = (const float*)d_in[9];
  const float* bv   = (const float*)d_in[10];
  const float* Wo   = (const float*)d_in[11];
  const float* bo   = (const float*)d_in[12];
  const float* lq1  = (const float*)d_in[13];
  const float* lk1  = (const float*)d_in[14];
  const float* lq2  = (const float*)d_in[15];
  const float* lk2  = (const float*)d_in[16];
  const float* gnw  = (const float*)d_in[17];
  const float* gnb  = (const float*)d_in[18];
  const float* W1   = (const float*)d_in[19];
  const float* b1   = (const float*)d_in[20];
  const float* Wg   = (const float*)d_in[21];
  const float* bg   = (const float*)d_in[22];
  const float* W2   = (const float*)d_in[23];
  const float* b2   = (const float*)d_in[24];

  const int B = 2, S = 2048, D = 1024, F = 4096;
  const int M = B * S;  // 4096
  const float qscale = 0.125f * 1.4426950408889634f;   // 1/sqrt(64) * log2e

  char* ws = (char*)d_ws;
  size_t off = 0;
  auto alloc = [&](size_t bytes) {
    char* p = ws + off;
    off += (bytes + 255) & ~(size_t)255;
    return p;
  };
  unsigned short* WqkvT = (unsigned short*)alloc((size_t)3 * D * D * 2);
  unsigned short* WoT = (unsigned short*)alloc((size_t)D * D * 2);
  unsigned short* W1T = (unsigned short*)alloc((size_t)F * D * 2);
  unsigned short* WgT = (unsigned short*)alloc((size_t)F * F * 2);
  unsigned short* W2T = (unsigned short*)alloc((size_t)D * F * 2);
  float*          lamw= (float*)alloc(256);
  float*          bqkv= (float*)alloc(3072 * 4);
  unsigned short* h_bf= (unsigned short*)alloc((size_t)M * D * 2);
  unsigned short* qkv = (unsigned short*)alloc((size_t)M * 3 * D * 2);
  unsigned short* o_bf= (unsigned short*)alloc((size_t)M * D * 2);
  float*          x1  = (float*)alloc((size_t)M * D * 4);
  unsigned short* x2b = (unsigned short*)alloc((size_t)M * D * 2);
  unsigned short* u_bf= (unsigned short*)alloc((size_t)M * F * 2);
  unsigned short* w_bf= h_bf;   // gated act reuses h span

  unsigned short* KP = (unsigned short*)x1;
  unsigned short* VT = u_bf + (size_t)12 * 1024 * 1024;

  // --- fused prep: weights + bias + lambda + LN1 ---
  mega_prep<<<7181 + M, 256, 0, stream>>>(Wq, Wk, Wv, Wo, W1, Wg, W2, WqkvT,
                                          bq, bk, bv, bqkv,
                                          lq1, lk1, lq2, lk2, lamw,
                                          x, ln1g, ln1b, h_bf, qscale);

  // --- attention sublayer ---
  gemm256<0><<<dim3(3 * D / 256, M / 256), 512, 0, stream>>>(h_bf, WqkvT, bqkv, nullptr, qkv, M, 3 * D, D);
  kv_prep<<<dim3(S / 64, 16), 256, 0, stream>>>(qkv, KP, VT);
  attn_kernel<<<dim3(512), 256, 0, stream>>>(qkv, KP, VT, lamw, gnw, gnb, o_bf);
  gemm128<1><<<dim3(D / 128, M / 128), 256, 0, stream>>>(o_bf, WoT, bo, x, nullptr, x1, M, D, D, 1.0f);

  // --- FFN sublayer ---
  ln_kernel<<<M, 256, 0, stream>>>(x1, ln2g, ln2b, x2b);
  gemm256<0><<<dim3(F / 256, M / 256), 512, 0, stream>>>(x2b, W1T, b1, nullptr, u_bf, M, F, D);
  gemm256<2><<<dim3(F / 256, M / 256), 512, 0, stream>>>(u_bf, WgT, bg, u_bf, w_bf, M, F, F);
  gemm128<2><<<dim3(D / 128, M / 128), 256, 0, stream>>>(w_bf, W2T, b2, nullptr, x2b, (float*)d_out, M, D, F, 1.0f);
}